// Round 2
// baseline (383.659 us; speedup 1.0000x reference)
//
#include <hip/hip_runtime.h>
#include <hip/hip_bf16.h>
#include <stdint.h>

// Problem constants
#define NHEADS 16
#define SEQ    2048
#define DMODEL 1024
#define DK     64

// Workspace layout (offsets in bf16 elements)
#define QB_OFF  0ull          // 8192x1024 bf16 copy of Q   (reused as Ocomb after projections)
#define KB_OFF  8388608ull    // 8192x1024 bf16 copy of K
#define VB_OFF  16777216ull   // 8192x1024 bf16 copy of V
#define WQ_OFF  25165824ull   // 1024x1024
#define WK_OFF  26214400ull
#define WV_OFF  27262976ull
#define WO_OFF  28311552ull
#define QH_OFF  29360128ull   // (B,H,T,dk) bf16, pre-scaled by log2e/8
#define KH_OFF  37748736ull   // (B,H,T,dk) bf16
#define VT_OFF  46137344ull   // (B,H,dk,T) bf16, key order phi-permuted per 32-window, masked cols zeroed
#define MSKF_OFF 54525952ull  // (B,T) bf16 mask (0/1.0), phi-permuted per 32-window
#define OC_OFF  0ull          // combined attention output (B,T,DMODEL) bf16 (aliases QB)

typedef __attribute__((ext_vector_type(8))) __bf16 bf16x8;
typedef __attribute__((ext_vector_type(4))) float  floatx4;

__device__ __forceinline__ unsigned short f2bf(float f) {
  unsigned int u = __float_as_uint(f);
  u += 0x7fffu + ((u >> 16) & 1u);   // round-to-nearest-even
  return (unsigned short)(u >> 16);
}

// async global->LDS, 16B per lane. LDS dest must be wave-uniform base + lane*16B.
__device__ __forceinline__ void gld_lds16(const void* g, void* l) {
  __builtin_amdgcn_global_load_lds(
      (const __attribute__((address_space(1))) unsigned int*)(g),
      (__attribute__((address_space(3))) unsigned int*)(uintptr_t)(l),
      16, 0, 0);
}

// ---------------------------------------------------------------------------
// fp32 -> bf16 cast (Q,K,V + 4 weights) + mask int -> phi-permuted bf16 (0/1)
// ---------------------------------------------------------------------------
struct CastArgs {
  const float* src[8];
  unsigned long long off[8];
  unsigned int n[8];
};

__global__ __launch_bounds__(256) void cast_bf16(CastArgs a, unsigned short* __restrict__ ws) {
  int ti = blockIdx.y;
  unsigned int n = a.n[ti];
  unsigned int stride = gridDim.x * blockDim.x * 4u;
  unsigned int i0 = (blockIdx.x * blockDim.x + threadIdx.x) * 4u;
  if (ti == 7) {
    // mask ints -> bf16 0/1.0, permuted within each 32-token window to match
    // the V^T key order: pm[phi(g)] = mask[g], phi: b2->b3, b3->b4, b4->b2.
    const int* s = (const int*)a.src[7];
    unsigned short* d = ws + a.off[7];
    for (unsigned int i = i0; i < n; i += stride) {
      int4 v = *(const int4*)(s + i);
      ushort4 o;
      o.x = v.x ? 0x3f80u : 0u;
      o.y = v.y ? 0x3f80u : 0u;
      o.z = v.z ? 0x3f80u : 0u;
      o.w = v.w ? 0x3f80u : 0u;
      unsigned int p = (i & ~31u) | ((i & 12u) << 1) | ((i & 16u) >> 2) | (i & 3u);
      *(ushort4*)(d + p) = o;   // i is 4-aligned -> p is 4-aligned, 4 contiguous shorts
    }
    return;
  }
  const float* s = a.src[ti];
  unsigned short* d = ws + a.off[ti];
  for (unsigned int i = i0; i < n; i += stride) {
    float4 v = *(const float4*)(s + i);
    ushort4 o;
    o.x = f2bf(v.x); o.y = f2bf(v.y); o.z = f2bf(v.z); o.w = f2bf(v.w);
    *(ushort4*)(d + i) = o;
  }
}

// ---------------------------------------------------------------------------
// Shared GEMM core: C[128x128] += A[128xK] * B[128xK]^T  (BT layout, K=1024)
// ---------------------------------------------------------------------------
__device__ __forceinline__ void gemm_core_128(
    const unsigned short* __restrict__ A, const unsigned short* __restrict__ Bw,
    int m0, int n0, unsigned short* As, unsigned short* Bs, floatx4 acc[4][4])
{
  int tid = threadIdx.x;
  int lane = tid & 63, l16 = lane & 15, quad = lane >> 4;
  int wave = tid >> 6, wm = wave >> 1, wn = wave & 1;
  #pragma unroll 1
  for (int kt = 0; kt < 32; ++kt) {
    __syncthreads();
    #pragma unroll
    for (int rnd = 0; rnd < 2; ++rnd) {
      int e = tid * 8 + rnd * 2048;
      int row = e >> 5, col = e & 31;
      gld_lds16(A  + (size_t)(m0 + row) * 1024 + kt * 32 + col, As + e);
      gld_lds16(Bw + (size_t)(n0 + row) * 1024 + kt * 32 + col, Bs + e);
    }
    __syncthreads();
    bf16x8 af[4], bfr[4];
    #pragma unroll
    for (int f = 0; f < 4; ++f) {
      af[f]  = *(const bf16x8*)(As + (wm * 64 + f * 16 + l16) * 32 + quad * 8);
      bfr[f] = *(const bf16x8*)(Bs + (wn * 64 + f * 16 + l16) * 32 + quad * 8);
    }
    #pragma unroll
    for (int fm = 0; fm < 4; ++fm)
      #pragma unroll
      for (int fn = 0; fn < 4; ++fn)
        acc[fm][fn] = __builtin_amdgcn_mfma_f32_16x16x32_bf16(af[fm], bfr[fn], acc[fm][fn], 0, 0, 0);
  }
}

// ---------------------------------------------------------------------------
// Projections with LDS-transposed coalesced epilogues.
//  z=0: q = (X_Q Wq^T + bq) * (log2e/8) -> (B,H,T,dk)
//  z=1: k = X_K Wk^T + bk               -> (B,H,T,dk)
//  z=2: V^T: D[d'][t] = (Wv[d',:]·X_V[t,:] + bv[d']) * mask[b][t]
//       -> (B,H,dk,T), t phi-permuted per 32
// grid (8, 64, 3)
// ---------------------------------------------------------------------------
__global__ __launch_bounds__(256) void proj_gemm(
    const unsigned short* __restrict__ wsc, unsigned short* __restrict__ ws,
    const float* __restrict__ bq, const float* __restrict__ bk, const float* __restrict__ bv)
{
  __shared__ unsigned short smem[17408];    // K-loop: As/Bs (8192); epilogue: C 128x136
  unsigned short* As = smem;
  unsigned short* Bs = smem + 4096;
  int z = blockIdx.z;
  int tid = threadIdx.x, lane = tid & 63, l16 = lane & 15, quad = lane >> 4;
  int wave = tid >> 6, wm = wave >> 1, wn = wave & 1;

  if (z < 2) {
    const unsigned short* A  = wsc + (z == 0 ? QB_OFF : KB_OFF);
    const unsigned short* Bw = wsc + (z == 0 ? WQ_OFF : WK_OFF);
    const float* bias = (z == 0) ? bq : bk;
    unsigned short* dst = ws + (z == 0 ? QH_OFF : KH_OFF);
    float scale = (z == 0) ? 0.18033688011111772f : 1.0f;  // (1/8)*log2(e) for q

    int m0 = blockIdx.y * 128, n0 = blockIdx.x * 128;
    floatx4 acc[4][4] = {};
    gemm_core_128(A, Bw, m0, n0, As, Bs, acc);

    __syncthreads();   // all As/Bs reads done before C overwrite
    #pragma unroll
    for (int fn = 0; fn < 4; ++fn) {
      int c = wn * 64 + fn * 16 + l16;
      float bvv = bias[n0 + c];
      #pragma unroll
      for (int fm = 0; fm < 4; ++fm)
        #pragma unroll
        for (int r = 0; r < 4; ++r) {
          int t = wm * 64 + fm * 16 + quad * 4 + r;
          smem[t * 136 + c] = f2bf((acc[fm][fn][r] + bvv) * scale);
        }
    }
    __syncthreads();
    #pragma unroll
    for (int it = 0; it < 8; ++it) {
      int e = it * 2048 + tid * 8;
      int t = e >> 7, c = e & 127;
      uint4 val = *(const uint4*)(smem + t * 136 + c);
      int m = m0 + t, b = m >> 11, tg = m & 2047;
      int h = (n0 + c) >> 6, d = (n0 + c) & 63;
      *(uint4*)(dst + ((size_t)(b * NHEADS + h) * SEQ + tg) * DK + d) = val;
    }
  } else {
    // V^T: per batch b, M=1024 (d'), N=2048 (t)
    int flat = blockIdx.y * 8 + blockIdx.x;          // [0,512)
    int b = flat >> 7, rem = flat & 127;
    int mt = rem >> 4, nt = rem & 15;
    int m0 = mt * 128, n0 = nt * 128;
    const unsigned short* A  = wsc + WV_OFF;                                  // Wv rows d'
    const unsigned short* Bw = wsc + VB_OFF + (size_t)b * SEQ * DMODEL;       // X_V rows t
    unsigned short* dst = ws + VT_OFF;

    floatx4 acc[4][4] = {};
    gemm_core_128(A, Bw, m0, n0, As, Bs, acc);

    // permuted bf16 mask for this batch: pm[n0 + tp] is mask of the token
    // stored at permuted column tp
    const unsigned short* pm = wsc + MSKF_OFF + (size_t)b * SEQ;
    int tpl[4];
    float mv[4];
    #pragma unroll
    for (int fn = 0; fn < 4; ++fn) {
      int t = wn * 64 + fn * 16 + l16;   // local token col [0,128)
      int tp = (t & ~31) | ((t & 12) << 1) | ((t & 16) >> 2) | (t & 3);  // phi^-1
      tpl[fn] = tp;
      mv[fn] = __uint_as_float((unsigned int)pm[n0 + tp] << 16);
    }

    __syncthreads();
    #pragma unroll
    for (int fm = 0; fm < 4; ++fm) {
      int mb = m0 + wm * 64 + fm * 16 + quad * 4;
      float4 bb4 = *(const float4*)(bv + mb);
      float bbv[4] = {bb4.x, bb4.y, bb4.z, bb4.w};
      #pragma unroll
      for (int r = 0; r < 4; ++r) {
        int mrow = wm * 64 + fm * 16 + quad * 4 + r;
        #pragma unroll
        for (int fn = 0; fn < 4; ++fn)
          smem[mrow * 136 + tpl[fn]] = f2bf((acc[fm][fn][r] + bbv[r]) * mv[fn]);
      }
    }
    __syncthreads();
    #pragma unroll
    for (int it = 0; it < 8; ++it) {
      int e = it * 2048 + tid * 8;
      int mrow = e >> 7, tcol = e & 127;
      uint4 val = *(const uint4*)(smem + mrow * 136 + tcol);
      int m = m0 + mrow, h = m >> 6, d = m & 63;
      *(uint4*)(dst + ((size_t)(b * NHEADS + h) * DK + d) * SEQ + n0 + tcol) = val;
    }
  }
}

// ---------------------------------------------------------------------------
// Fused flash attention, S^T formulation, fixed-max softmax (log2-domain).
// R7: 256 threads (4 waves), 256 q per block, K/V/mask DOUBLE-BUFFERED in LDS
//     with jt+1 prefetch issued before jt's compute -> load latency hides
//     under MFMA/exp2; ONE barrier per jt (vmcnt(0) drain lands after
//     ~1500 cyc of compute). grid (8, 64) = 512 blocks = 2/CU, 66 KB LDS,
//     8 waves/CU (unchanged).
// ---------------------------------------------------------------------------
#define ABUF 16512   // shorts per buffer: 8192 K + 8192 V + 128 mask (+pad)

__global__ __launch_bounds__(256, 2) void attn_fused(
    const unsigned short* __restrict__ wsc, unsigned short* __restrict__ ws)
{
  __shared__ unsigned short smem[2 * ABUF];   // 66048 B

  int qt = blockIdx.x, bh = blockIdx.y;
  int b = bh >> 4, h = bh & 15;
  int tid = threadIdx.x, wave = tid >> 6, lane = tid & 63, l16 = lane & 15, quad = lane >> 4;
  int wq = wave * 64;

  const unsigned short* qh = wsc + QH_OFF + (size_t)bh * SEQ * DK;
  const unsigned short* kh = wsc + KH_OFF + (size_t)bh * SEQ * DK;
  const unsigned short* vt = wsc + VT_OFF + (size_t)bh * DK * SEQ;
  const unsigned short* pm = wsc + MSKF_OFF + (size_t)b * SEQ;

  // ---- stage Q tile (256 q x 64 d) into smem low region, grab B-frags ----
  #pragma unroll
  for (int kk = 0; kk < 2; ++kk)
    #pragma unroll
    for (int rnd = 0; rnd < 4; ++rnd) {
      int e = tid * 8 + rnd * 2048;
      int row = e >> 5, col = e & 31;
      gld_lds16(qh + (size_t)(qt * 256 + row) * DK + kk * 32 + col, smem + kk * 8192 + e);
    }
  __syncthreads();
  bf16x8 qf[4][2];
  #pragma unroll
  for (int fq = 0; fq < 4; ++fq)
    #pragma unroll
    for (int kk = 0; kk < 2; ++kk)
      qf[fq][kk] = *(const bf16x8*)(smem + kk * 8192 + (wq + fq * 16 + l16) * 32 + quad * 8);
  __syncthreads();   // all waves done reading Q region before buf0 staging lands

  // ---- stage jt=0 into buffer 0 ----
  {
    unsigned short* Kb = smem;
    unsigned short* Vb = smem + 8192;
    unsigned short* Mb = smem + 16384;
    #pragma unroll
    for (int kk = 0; kk < 2; ++kk)
      #pragma unroll
      for (int rnd = 0; rnd < 2; ++rnd) {
        int e = tid * 8 + rnd * 2048;
        int row = e >> 5, col = e & 31;
        gld_lds16(kh + (size_t)row * DK + kk * 32 + col, Kb + kk * 4096 + e);
      }
    #pragma unroll
    for (int kk = 0; kk < 4; ++kk) {
      int e = tid * 8;
      int row = e >> 5, col = e & 31;
      gld_lds16(vt + (size_t)row * SEQ + kk * 32 + col, Vb + kk * 2048 + e);
    }
    if (tid < 16)
      gld_lds16(pm + tid * 8, Mb + tid * 8);
  }
  __syncthreads();   // buf0 ready (vmcnt drained here, prologue only)

  floatx4 o[4][4] = {};
  floatx4 osum[4] = {};          // denominator accumulators (mask-row MFMA)
  const floatx4 zero4 = {};
  int cur = 0;

  #pragma unroll 1
  for (int jt = 0; jt < 16; ++jt) {
    unsigned short* Kс = smem + cur * ABUF;            // current K
    unsigned short* Vс = smem + cur * ABUF + 8192;     // current V
    unsigned short* Mс = smem + cur * ABUF + 16384;    // current mask

    // ---- prefetch jt+1 into the other buffer (stays in flight thru compute)
    if (jt < 15) {
      int nxt = cur ^ 1;
      unsigned short* Kb = smem + nxt * ABUF;
      unsigned short* Vb = smem + nxt * ABUF + 8192;
      unsigned short* Mb = smem + nxt * ABUF + 16384;
      const unsigned short* khn = kh + (size_t)(jt + 1) * 128 * DK;
      const unsigned short* vtn = vt + (jt + 1) * 128;
      #pragma unroll
      for (int kk = 0; kk < 2; ++kk)
        #pragma unroll
        for (int rnd = 0; rnd < 2; ++rnd) {
          int e = tid * 8 + rnd * 2048;
          int row = e >> 5, col = e & 31;
          gld_lds16(khn + (size_t)row * DK + kk * 32 + col, Kb + kk * 4096 + e);
        }
      #pragma unroll
      for (int kk = 0; kk < 4; ++kk) {
        int e = tid * 8;
        int row = e >> 5, col = e & 31;
        gld_lds16(vtn + (size_t)row * SEQ + kk * 32 + col, Vb + kk * 2048 + e);
      }
      if (tid < 16)
        gld_lds16(pm + (jt + 1) * 128 + tid * 8, Mb + tid * 8);
    }

    // ---- compute jt from current buffer ----
    #pragma unroll
    for (int w = 0; w < 4; ++w) {
      floatx4 s[2][4];
      #pragma unroll
      for (int f2 = 0; f2 < 2; ++f2) {
        int fk = 2 * w + f2;
        bf16x8 kf0 = *(const bf16x8*)(Kс +        (fk * 16 + l16) * 32 + quad * 8);
        bf16x8 kf1 = *(const bf16x8*)(Kс + 4096 + (fk * 16 + l16) * 32 + quad * 8);
        #pragma unroll
        for (int fq = 0; fq < 4; ++fq) {
          s[f2][fq] = __builtin_amdgcn_mfma_f32_16x16x32_bf16(kf0, qf[fq][0], zero4, 0, 0, 0);
          s[f2][fq] = __builtin_amdgcn_mfma_f32_16x16x32_bf16(kf1, qf[fq][1], s[f2][fq], 0, 0, 0);
        }
      }
      #pragma unroll
      for (int f2 = 0; f2 < 2; ++f2)
        #pragma unroll
        for (int fq = 0; fq < 4; ++fq)
          #pragma unroll
          for (int r = 0; r < 4; ++r)
            s[f2][fq][r] = __builtin_amdgcn_exp2f(s[f2][fq][r]);

      union { unsigned int u[4]; bf16x8 v; } pf[4];
      #pragma unroll
      for (int fq = 0; fq < 4; ++fq) {
        asm("v_cvt_pk_bf16_f32 %0, %1, %2" : "=v"(pf[fq].u[0]) : "v"(s[0][fq][0]), "v"(s[0][fq][1]));
        asm("v_cvt_pk_bf16_f32 %0, %1, %2" : "=v"(pf[fq].u[1]) : "v"(s[0][fq][2]), "v"(s[0][fq][3]));
        asm("v_cvt_pk_bf16_f32 %0, %1, %2" : "=v"(pf[fq].u[2]) : "v"(s[1][fq][0]), "v"(s[1][fq][1]));
        asm("v_cvt_pk_bf16_f32 %0, %1, %2" : "=v"(pf[fq].u[3]) : "v"(s[1][fq][2]), "v"(s[1][fq][3]));
      }

      // denominator: A = mask value in ALL 16 rows -> every C row holds
      // sum_k mask[k]*p[k][q]; broadcast LDS read (same addr for all l16)
      bf16x8 mvf = *(const bf16x8*)(Mс + w * 32 + quad * 8);
      #pragma unroll
      for (int fq = 0; fq < 4; ++fq)
        osum[fq] = __builtin_amdgcn_mfma_f32_16x16x32_bf16(mvf, pf[fq].v, osum[fq], 0, 0, 0);

      #pragma unroll
      for (int fd = 0; fd < 4; ++fd) {
        bf16x8 vf = *(const bf16x8*)(Vс + w * 2048 + (fd * 16 + l16) * 32 + quad * 8);
        #pragma unroll
        for (int fq = 0; fq < 4; ++fq)
          o[fd][fq] = __builtin_amdgcn_mfma_f32_16x16x32_bf16(vf, pf[fq].v, o[fd][fq], 0, 0, 0);
      }
    }

    __syncthreads();   // prefetch landed (vmcnt) + all reads of cur done (lgkm)
    cur ^= 1;
  }

  // every lane already holds its q's denominator (all osum rows identical)
  float inv[4];
  #pragma unroll
  for (int fq = 0; fq < 4; ++fq)
    inv[fq] = __builtin_amdgcn_rcpf(osum[fq][0]);

  unsigned short* Ot = smem;   // 256 q x 72 (64 d + 8 pad)
  #pragma unroll
  for (int fd = 0; fd < 4; ++fd)
    #pragma unroll
    for (int fq = 0; fq < 4; ++fq)
      #pragma unroll
      for (int r = 0; r < 4; ++r) {
        int q = wq + fq * 16 + l16;
        int d = fd * 16 + quad * 4 + r;
        Ot[q * 72 + d] = f2bf(o[fd][fq][r] * inv[fq]);
      }
  __syncthreads();
  unsigned short* oc = ws + OC_OFF;
  #pragma unroll
  for (int rr = 0; rr < 8; ++rr) {
    int e = rr * 2048 + tid * 8;
    int q = e >> 6, off = e & 63;
    uint4 val = *(const uint4*)(Ot + q * 72 + off);
    *(uint4*)(oc + ((size_t)(b * SEQ + qt * 256 + q)) * DMODEL + h * DK + off) = val;
  }
}

// ---------------------------------------------------------------------------
// Output projection: out = Ocomb Wo^T + bo  (fp32 out)
// ---------------------------------------------------------------------------
__global__ __launch_bounds__(256) void out_gemm(
    const unsigned short* __restrict__ wsc, const float* __restrict__ bo,
    float* __restrict__ out)
{
  __shared__ unsigned short smem[8192];
  unsigned short* As = smem;
  unsigned short* Bs = smem + 4096;
  int m0 = blockIdx.y * 128, n0 = blockIdx.x * 128;
  floatx4 acc[4][4] = {};
  gemm_core_128(wsc + OC_OFF, wsc + WO_OFF, m0, n0, As, Bs, acc);

  int tid = threadIdx.x, lane = tid & 63, l16 = lane & 15, quad = lane >> 4;
  int wave = tid >> 6, wm = wave >> 1, wn = wave & 1;
  #pragma unroll
  for (int fn = 0; fn < 4; ++fn) {
    int n = n0 + wn * 64 + fn * 16 + l16;
    float bvv = bo[n];
    #pragma unroll
    for (int fm = 0; fm < 4; ++fm)
      #pragma unroll
      for (int r = 0; r < 4; ++r) {
        int m = m0 + wm * 64 + fm * 16 + quad * 4 + r;
        out[(size_t)m * DMODEL + n] = acc[fm][fn][r] + bvv;
      }
  }
}

// ---------------------------------------------------------------------------
extern "C" void kernel_launch(void* const* d_in, const int* in_sizes, int n_in,
                              void* d_out, int out_size, void* d_ws, size_t ws_size,
                              hipStream_t stream) {
  const float* Q    = (const float*)d_in[0];
  const float* K    = (const float*)d_in[1];
  const float* V    = (const float*)d_in[2];
  const float* bq   = (const float*)d_in[5];
  const float* bk   = (const float*)d_in[7];
  const float* bv   = (const float*)d_in[9];
  const float* bo   = (const float*)d_in[11];
  unsigned short* ws = (unsigned short*)d_ws;
  float* out = (float*)d_out;

  CastArgs ca;
  ca.src[0] = Q;  ca.src[1] = K;  ca.src[2] = V;
  ca.src[3] = (const float*)d_in[4]; ca.src[4] = (const float*)d_in[6];
  ca.src[5] = (const float*)d_in[8]; ca.src[6] = (const float*)d_in[10];
  ca.src[7] = (const float*)d_in[3];   // mask ints
  ca.off[0] = QB_OFF; ca.off[1] = KB_OFF; ca.off[2] = VB_OFF;
  ca.off[3] = WQ_OFF; ca.off[4] = WK_OFF; ca.off[5] = WV_OFF; ca.off[6] = WO_OFF;
  ca.off[7] = MSKF_OFF;
  ca.n[0] = ca.n[1] = ca.n[2] = 8388608u;
  ca.n[3] = ca.n[4] = ca.n[5] = ca.n[6] = 1048576u;
  ca.n[7] = 8192u;

  hipLaunchKernelGGL(cast_bf16, dim3(2048, 8), dim3(256), 0, stream, ca, ws);
  hipLaunchKernelGGL(proj_gemm, dim3(8, 64, 3), dim3(256), 0, stream, ws, ws, bq, bk, bv);
  hipLaunchKernelGGL(attn_fused, dim3(16, 64), dim3(256), 0, stream, ws, ws);
  hipLaunchKernelGGL(out_gemm, dim3(8, 64), dim3(256), 0, stream, ws, bo, out);
}

// Round 3
// 339.076 us; speedup vs baseline: 1.1315x; 1.1315x over previous
//
#include <hip/hip_runtime.h>
#include <hip/hip_bf16.h>
#include <stdint.h>

// Problem constants
#define NHEADS 16
#define SEQ    2048
#define DMODEL 1024
#define DK     64

// Workspace layout (offsets in bf16 elements)
#define QB_OFF  0ull          // 8192x1024 bf16 copy of Q   (reused as Ocomb after projections)
#define KB_OFF  8388608ull    // 8192x1024 bf16 copy of K
#define VB_OFF  16777216ull   // 8192x1024 bf16 copy of V
#define WQ_OFF  25165824ull   // 1024x1024
#define WK_OFF  26214400ull
#define WV_OFF  27262976ull
#define WO_OFF  28311552ull
#define QH_OFF  29360128ull   // (B,H,T,dk) bf16, pre-scaled by log2e/8
#define KH_OFF  37748736ull   // (B,H,T,dk) bf16
#define VT_OFF  46137344ull   // (B,H,dk,T) bf16, key order phi-permuted per 32-window, masked cols zeroed
#define MSKF_OFF 54525952ull  // (B,T) bf16 mask (0/1.0), phi-permuted per 32-window
#define OC_OFF  0ull          // combined attention output (B,T,DMODEL) bf16 (aliases QB)

typedef __attribute__((ext_vector_type(8))) __bf16 bf16x8;
typedef __attribute__((ext_vector_type(4))) float  floatx4;

__device__ __forceinline__ unsigned short f2bf(float f) {
  unsigned int u = __float_as_uint(f);
  u += 0x7fffu + ((u >> 16) & 1u);   // round-to-nearest-even
  return (unsigned short)(u >> 16);
}

// async global->LDS, 16B per lane. LDS dest must be wave-uniform base + lane*16B.
__device__ __forceinline__ void gld_lds16(const void* g, void* l) {
  __builtin_amdgcn_global_load_lds(
      (const __attribute__((address_space(1))) unsigned int*)(g),
      (__attribute__((address_space(3))) unsigned int*)(uintptr_t)(l),
      16, 0, 0);
}

// ---------------------------------------------------------------------------
// fp32 -> bf16 cast (Q,K,V + 4 weights) + mask int -> phi-permuted bf16 (0/1)
// ---------------------------------------------------------------------------
struct CastArgs {
  const float* src[8];
  unsigned long long off[8];
  unsigned int n[8];
};

__global__ __launch_bounds__(256) void cast_bf16(CastArgs a, unsigned short* __restrict__ ws) {
  int ti = blockIdx.y;
  unsigned int n = a.n[ti];
  unsigned int stride = gridDim.x * blockDim.x * 4u;
  unsigned int i0 = (blockIdx.x * blockDim.x + threadIdx.x) * 4u;
  if (ti == 7) {
    // mask ints -> bf16 0/1.0, permuted within each 32-token window to match
    // the V^T key order: pm[phi(g)] = mask[g], phi: b2->b3, b3->b4, b4->b2.
    const int* s = (const int*)a.src[7];
    unsigned short* d = ws + a.off[7];
    for (unsigned int i = i0; i < n; i += stride) {
      int4 v = *(const int4*)(s + i);
      ushort4 o;
      o.x = v.x ? 0x3f80u : 0u;
      o.y = v.y ? 0x3f80u : 0u;
      o.z = v.z ? 0x3f80u : 0u;
      o.w = v.w ? 0x3f80u : 0u;
      unsigned int p = (i & ~31u) | ((i & 12u) << 1) | ((i & 16u) >> 2) | (i & 3u);
      *(ushort4*)(d + p) = o;   // i is 4-aligned -> p is 4-aligned, 4 contiguous shorts
    }
    return;
  }
  const float* s = a.src[ti];
  unsigned short* d = ws + a.off[ti];
  for (unsigned int i = i0; i < n; i += stride) {
    float4 v = *(const float4*)(s + i);
    ushort4 o;
    o.x = f2bf(v.x); o.y = f2bf(v.y); o.z = f2bf(v.z); o.w = f2bf(v.w);
    *(ushort4*)(d + i) = o;
  }
}

// ---------------------------------------------------------------------------
// Shared GEMM core: C[128x128] += A[128xK] * B[128xK]^T  (BT layout, K=1024)
// ---------------------------------------------------------------------------
__device__ __forceinline__ void gemm_core_128(
    const unsigned short* __restrict__ A, const unsigned short* __restrict__ Bw,
    int m0, int n0, unsigned short* As, unsigned short* Bs, floatx4 acc[4][4])
{
  int tid = threadIdx.x;
  int lane = tid & 63, l16 = lane & 15, quad = lane >> 4;
  int wave = tid >> 6, wm = wave >> 1, wn = wave & 1;
  #pragma unroll 1
  for (int kt = 0; kt < 32; ++kt) {
    __syncthreads();
    #pragma unroll
    for (int rnd = 0; rnd < 2; ++rnd) {
      int e = tid * 8 + rnd * 2048;
      int row = e >> 5, col = e & 31;
      gld_lds16(A  + (size_t)(m0 + row) * 1024 + kt * 32 + col, As + e);
      gld_lds16(Bw + (size_t)(n0 + row) * 1024 + kt * 32 + col, Bs + e);
    }
    __syncthreads();
    bf16x8 af[4], bfr[4];
    #pragma unroll
    for (int f = 0; f < 4; ++f) {
      af[f]  = *(const bf16x8*)(As + (wm * 64 + f * 16 + l16) * 32 + quad * 8);
      bfr[f] = *(const bf16x8*)(Bs + (wn * 64 + f * 16 + l16) * 32 + quad * 8);
    }
    #pragma unroll
    for (int fm = 0; fm < 4; ++fm)
      #pragma unroll
      for (int fn = 0; fn < 4; ++fn)
        acc[fm][fn] = __builtin_amdgcn_mfma_f32_16x16x32_bf16(af[fm], bfr[fn], acc[fm][fn], 0, 0, 0);
  }
}

// ---------------------------------------------------------------------------
// Projections with LDS-transposed coalesced epilogues.
//  z=0: q = (X_Q Wq^T + bq) * (log2e/8) -> (B,H,T,dk)
//  z=1: k = X_K Wk^T + bk               -> (B,H,T,dk)
//  z=2: V^T: D[d'][t] = (Wv[d',:]·X_V[t,:] + bv[d']) * mask[b][t]
//       -> (B,H,dk,T), t phi-permuted per 32
// grid (8, 64, 3)
// ---------------------------------------------------------------------------
__global__ __launch_bounds__(256) void proj_gemm(
    const unsigned short* __restrict__ wsc, unsigned short* __restrict__ ws,
    const float* __restrict__ bq, const float* __restrict__ bk, const float* __restrict__ bv)
{
  __shared__ unsigned short smem[17408];    // K-loop: As/Bs (8192); epilogue: C 128x136
  unsigned short* As = smem;
  unsigned short* Bs = smem + 4096;
  int z = blockIdx.z;
  int tid = threadIdx.x, lane = tid & 63, l16 = lane & 15, quad = lane >> 4;
  int wave = tid >> 6, wm = wave >> 1, wn = wave & 1;

  if (z < 2) {
    const unsigned short* A  = wsc + (z == 0 ? QB_OFF : KB_OFF);
    const unsigned short* Bw = wsc + (z == 0 ? WQ_OFF : WK_OFF);
    const float* bias = (z == 0) ? bq : bk;
    unsigned short* dst = ws + (z == 0 ? QH_OFF : KH_OFF);
    float scale = (z == 0) ? 0.18033688011111772f : 1.0f;  // (1/8)*log2(e) for q

    int m0 = blockIdx.y * 128, n0 = blockIdx.x * 128;
    floatx4 acc[4][4] = {};
    gemm_core_128(A, Bw, m0, n0, As, Bs, acc);

    __syncthreads();   // all As/Bs reads done before C overwrite
    #pragma unroll
    for (int fn = 0; fn < 4; ++fn) {
      int c = wn * 64 + fn * 16 + l16;
      float bvv = bias[n0 + c];
      #pragma unroll
      for (int fm = 0; fm < 4; ++fm)
        #pragma unroll
        for (int r = 0; r < 4; ++r) {
          int t = wm * 64 + fm * 16 + quad * 4 + r;
          smem[t * 136 + c] = f2bf((acc[fm][fn][r] + bvv) * scale);
        }
    }
    __syncthreads();
    #pragma unroll
    for (int it = 0; it < 8; ++it) {
      int e = it * 2048 + tid * 8;
      int t = e >> 7, c = e & 127;
      uint4 val = *(const uint4*)(smem + t * 136 + c);
      int m = m0 + t, b = m >> 11, tg = m & 2047;
      int h = (n0 + c) >> 6, d = (n0 + c) & 63;
      *(uint4*)(dst + ((size_t)(b * NHEADS + h) * SEQ + tg) * DK + d) = val;
    }
  } else {
    // V^T: per batch b, M=1024 (d'), N=2048 (t)
    int flat = blockIdx.y * 8 + blockIdx.x;          // [0,512)
    int b = flat >> 7, rem = flat & 127;
    int mt = rem >> 4, nt = rem & 15;
    int m0 = mt * 128, n0 = nt * 128;
    const unsigned short* A  = wsc + WV_OFF;                                  // Wv rows d'
    const unsigned short* Bw = wsc + VB_OFF + (size_t)b * SEQ * DMODEL;       // X_V rows t
    unsigned short* dst = ws + VT_OFF;

    floatx4 acc[4][4] = {};
    gemm_core_128(A, Bw, m0, n0, As, Bs, acc);

    // permuted bf16 mask for this batch: pm[n0 + tp] is mask of the token
    // stored at permuted column tp
    const unsigned short* pm = wsc + MSKF_OFF + (size_t)b * SEQ;
    int tpl[4];
    float mv[4];
    #pragma unroll
    for (int fn = 0; fn < 4; ++fn) {
      int t = wn * 64 + fn * 16 + l16;   // local token col [0,128)
      int tp = (t & ~31) | ((t & 12) << 1) | ((t & 16) >> 2) | (t & 3);  // phi^-1
      tpl[fn] = tp;
      mv[fn] = __uint_as_float((unsigned int)pm[n0 + tp] << 16);
    }

    __syncthreads();
    #pragma unroll
    for (int fm = 0; fm < 4; ++fm) {
      int mb = m0 + wm * 64 + fm * 16 + quad * 4;
      float4 bb4 = *(const float4*)(bv + mb);
      float bbv[4] = {bb4.x, bb4.y, bb4.z, bb4.w};
      #pragma unroll
      for (int r = 0; r < 4; ++r) {
        int mrow = wm * 64 + fm * 16 + quad * 4 + r;
        #pragma unroll
        for (int fn = 0; fn < 4; ++fn)
          smem[mrow * 136 + tpl[fn]] = f2bf((acc[fm][fn][r] + bbv[r]) * mv[fn]);
      }
    }
    __syncthreads();
    #pragma unroll
    for (int it = 0; it < 8; ++it) {
      int e = it * 2048 + tid * 8;
      int mrow = e >> 7, tcol = e & 127;
      uint4 val = *(const uint4*)(smem + mrow * 136 + tcol);
      int m = m0 + mrow, h = m >> 6, d = m & 63;
      *(uint4*)(dst + ((size_t)(b * NHEADS + h) * DK + d) * SEQ + n0 + tcol) = val;
    }
  }
}

// ---------------------------------------------------------------------------
// Fused flash attention, S^T formulation, fixed-max softmax (log2-domain).
// 64 q per wave. block = 128 threads (2 waves), 128 q per block.
// grid (16, 64) = 1024 blocks = 4/CU.
// R8: revert to R6 single-buffer structure (R7 dbuf regressed: concurrent
//     gld_lds writes contended with compute ds_reads; kernel is fetch-bound).
//     + XCD-locality swizzle: all 16 q-blocks of one (b,h) map to the SAME
//     XCD (block fid -> xcd = fid&7), so K/V (512 KB/bh, 8 bh/XCD = 4 MB)
//     stays L2-resident -> HBM re-fetch of K/V eliminated.
// ---------------------------------------------------------------------------
__global__ __launch_bounds__(128, 2) void attn_fused(
    const unsigned short* __restrict__ wsc, unsigned short* __restrict__ ws)
{
  __shared__ unsigned short smem[16640];   // 33280 B
  unsigned short* Ks  = smem;              // 128 keys x 64 d (2 chunks 128x32) = 8192
  unsigned short* Vts = smem + 8192;       // 64 d x 128 keys (4 chunks 64x32)  = 8192
  unsigned short* MskB = smem + 16384;     // 128 bf16 mask (phi-permuted key order)

  // XCD-locality swizzle: blocks dispatch round-robin over 8 XCDs by flat id.
  // Give XCD x the 8 bh's [x*8, x*8+8) and all 16 qt of each.
  int fid = blockIdx.y * gridDim.x + blockIdx.x;   // [0,1024)
  int xcd = fid & 7, slot = fid >> 3;              // slot in [0,128)
  int bh = xcd * 8 + (slot >> 4);
  int qt = slot & 15;
  int b = bh >> 4, h = bh & 15;
  int tid = threadIdx.x, wave = tid >> 6, lane = tid & 63, l16 = lane & 15, quad = lane >> 4;
  int wq = wave * 64;

  const unsigned short* qh = wsc + QH_OFF + (size_t)bh * SEQ * DK;
  const unsigned short* kh = wsc + KH_OFF + (size_t)bh * SEQ * DK;
  const unsigned short* vt = wsc + VT_OFF + (size_t)bh * DK * SEQ;
  const unsigned short* pm = wsc + MSKF_OFF + (size_t)b * SEQ;

  // stage Q tile (128x64) into Ks region, read B-operand frags, then release
  #pragma unroll
  for (int kk = 0; kk < 2; ++kk)
    #pragma unroll
    for (int rnd = 0; rnd < 4; ++rnd) {
      int e = tid * 8 + rnd * 1024;
      int row = e >> 5, col = e & 31;
      gld_lds16(qh + (size_t)(qt * 128 + row) * DK + kk * 32 + col, Ks + kk * 4096 + e);
    }
  __syncthreads();
  bf16x8 qf[4][2];
  #pragma unroll
  for (int fq = 0; fq < 4; ++fq)
    #pragma unroll
    for (int kk = 0; kk < 2; ++kk)
      qf[fq][kk] = *(const bf16x8*)(Ks + kk * 4096 + (wq + fq * 16 + l16) * 32 + quad * 8);

  floatx4 o[4][4] = {};
  floatx4 osum[4] = {};          // denominator accumulators (mask-row MFMA)
  const floatx4 zero4 = {};

  #pragma unroll 1
  for (int jt = 0; jt < 16; ++jt) {
    __syncthreads();   // prior LDS reads (incl. Q frags on jt==0) complete
    #pragma unroll
    for (int kk = 0; kk < 2; ++kk)
      #pragma unroll
      for (int rnd = 0; rnd < 4; ++rnd) {
        int e = tid * 8 + rnd * 1024;
        int row = e >> 5, col = e & 31;
        gld_lds16(kh + (size_t)(jt * 128 + row) * DK + kk * 32 + col, Ks + kk * 4096 + e);
      }
    #pragma unroll
    for (int kk = 0; kk < 4; ++kk)
      #pragma unroll
      for (int rnd = 0; rnd < 2; ++rnd) {
        int e = tid * 8 + rnd * 1024;
        int row = e >> 5, col = e & 31;
        gld_lds16(vt + (size_t)row * SEQ + jt * 128 + kk * 32 + col, Vts + kk * 2048 + e);
      }
    if (tid < 16)
      gld_lds16(pm + jt * 128 + tid * 8, MskB + tid * 8);
    __syncthreads();

    // per-32-key chunk: S^T -> exp2 -> pack -> denom-MFMA -> PV
    #pragma unroll
    for (int w = 0; w < 4; ++w) {
      floatx4 s[2][4];
      #pragma unroll
      for (int f2 = 0; f2 < 2; ++f2) {
        int fk = 2 * w + f2;
        bf16x8 kf0 = *(const bf16x8*)(Ks +        (fk * 16 + l16) * 32 + quad * 8);
        bf16x8 kf1 = *(const bf16x8*)(Ks + 4096 + (fk * 16 + l16) * 32 + quad * 8);
        #pragma unroll
        for (int fq = 0; fq < 4; ++fq) {
          s[f2][fq] = __builtin_amdgcn_mfma_f32_16x16x32_bf16(kf0, qf[fq][0], zero4, 0, 0, 0);
          s[f2][fq] = __builtin_amdgcn_mfma_f32_16x16x32_bf16(kf1, qf[fq][1], s[f2][fq], 0, 0, 0);
        }
      }
      #pragma unroll
      for (int f2 = 0; f2 < 2; ++f2)
        #pragma unroll
        for (int fq = 0; fq < 4; ++fq)
          #pragma unroll
          for (int r = 0; r < 4; ++r)
            s[f2][fq][r] = __builtin_amdgcn_exp2f(s[f2][fq][r]);

      union { unsigned int u[4]; bf16x8 v; } pf[4];
      #pragma unroll
      for (int fq = 0; fq < 4; ++fq) {
        asm("v_cvt_pk_bf16_f32 %0, %1, %2" : "=v"(pf[fq].u[0]) : "v"(s[0][fq][0]), "v"(s[0][fq][1]));
        asm("v_cvt_pk_bf16_f32 %0, %1, %2" : "=v"(pf[fq].u[1]) : "v"(s[0][fq][2]), "v"(s[0][fq][3]));
        asm("v_cvt_pk_bf16_f32 %0, %1, %2" : "=v"(pf[fq].u[2]) : "v"(s[1][fq][0]), "v"(s[1][fq][1]));
        asm("v_cvt_pk_bf16_f32 %0, %1, %2" : "=v"(pf[fq].u[3]) : "v"(s[1][fq][2]), "v"(s[1][fq][3]));
      }

      // denominator: A = mask value in ALL 16 rows -> every C row holds
      // sum_k mask[k]*p[k][q]; broadcast LDS read (same addr for all l16)
      bf16x8 mvf = *(const bf16x8*)(MskB + w * 32 + quad * 8);
      #pragma unroll
      for (int fq = 0; fq < 4; ++fq)
        osum[fq] = __builtin_amdgcn_mfma_f32_16x16x32_bf16(mvf, pf[fq].v, osum[fq], 0, 0, 0);

      #pragma unroll
      for (int fd = 0; fd < 4; ++fd) {
        bf16x8 vf = *(const bf16x8*)(Vts + w * 2048 + (fd * 16 + l16) * 32 + quad * 8);
        #pragma unroll
        for (int fq = 0; fq < 4; ++fq)
          o[fd][fq] = __builtin_amdgcn_mfma_f32_16x16x32_bf16(vf, pf[fq].v, o[fd][fq], 0, 0, 0);
      }
    }
  }

  // every lane already holds its q's denominator (all osum rows identical)
  float inv[4];
  #pragma unroll
  for (int fq = 0; fq < 4; ++fq)
    inv[fq] = __builtin_amdgcn_rcpf(osum[fq][0]);

  __syncthreads();
  unsigned short* Ot = smem;   // 128 q x 72 (64 d + 8 pad)
  #pragma unroll
  for (int fd = 0; fd < 4; ++fd)
    #pragma unroll
    for (int fq = 0; fq < 4; ++fq)
      #pragma unroll
      for (int r = 0; r < 4; ++r) {
        int q = wq + fq * 16 + l16;
        int d = fd * 16 + quad * 4 + r;
        Ot[q * 72 + d] = f2bf(o[fd][fq][r] * inv[fq]);
      }
  __syncthreads();
  unsigned short* oc = ws + OC_OFF;
  #pragma unroll
  for (int rr = 0; rr < 8; ++rr) {
    int e = rr * 1024 + tid * 8;
    int q = e >> 6, off = e & 63;
    uint4 val = *(const uint4*)(Ot + q * 72 + off);
    *(uint4*)(oc + ((size_t)(b * SEQ + qt * 128 + q)) * DMODEL + h * DK + off) = val;
  }
}

// ---------------------------------------------------------------------------
// Output projection: out = Ocomb Wo^T + bo  (fp32 out)
// ---------------------------------------------------------------------------
__global__ __launch_bounds__(256) void out_gemm(
    const unsigned short* __restrict__ wsc, const float* __restrict__ bo,
    float* __restrict__ out)
{
  __shared__ unsigned short smem[8192];
  unsigned short* As = smem;
  unsigned short* Bs = smem + 4096;
  int m0 = blockIdx.y * 128, n0 = blockIdx.x * 128;
  floatx4 acc[4][4] = {};
  gemm_core_128(wsc + OC_OFF, wsc + WO_OFF, m0, n0, As, Bs, acc);

  int tid = threadIdx.x, lane = tid & 63, l16 = lane & 15, quad = lane >> 4;
  int wave = tid >> 6, wm = wave >> 1, wn = wave & 1;
  #pragma unroll
  for (int fn = 0; fn < 4; ++fn) {
    int n = n0 + wn * 64 + fn * 16 + l16;
    float bvv = bo[n];
    #pragma unroll
    for (int fm = 0; fm < 4; ++fm)
      #pragma unroll
      for (int r = 0; r < 4; ++r) {
        int m = m0 + wm * 64 + fm * 16 + quad * 4 + r;
        out[(size_t)m * DMODEL + n] = acc[fm][fn][r] + bvv;
      }
  }
}

// ---------------------------------------------------------------------------
extern "C" void kernel_launch(void* const* d_in, const int* in_sizes, int n_in,
                              void* d_out, int out_size, void* d_ws, size_t ws_size,
                              hipStream_t stream) {
  const float* Q    = (const float*)d_in[0];
  const float* K    = (const float*)d_in[1];
  const float* V    = (const float*)d_in[2];
  const float* bq   = (const float*)d_in[5];
  const float* bk   = (const float*)d_in[7];
  const float* bv   = (const float*)d_in[9];
  const float* bo   = (const float*)d_in[11];
  unsigned short* ws = (unsigned short*)d_ws;
  float* out = (float*)d_out;

  CastArgs ca;
  ca.src[0] = Q;  ca.src[1] = K;  ca.src[2] = V;
  ca.src[3] = (const float*)d_in[4]; ca.src[4] = (const float*)d_in[6];
  ca.src[5] = (const float*)d_in[8]; ca.src[6] = (const float*)d_in[10];
  ca.src[7] = (const float*)d_in[3];   // mask ints
  ca.off[0] = QB_OFF; ca.off[1] = KB_OFF; ca.off[2] = VB_OFF;
  ca.off[3] = WQ_OFF; ca.off[4] = WK_OFF; ca.off[5] = WV_OFF; ca.off[6] = WO_OFF;
  ca.off[7] = MSKF_OFF;
  ca.n[0] = ca.n[1] = ca.n[2] = 8388608u;
  ca.n[3] = ca.n[4] = ca.n[5] = ca.n[6] = 1048576u;
  ca.n[7] = 8192u;

  hipLaunchKernelGGL(cast_bf16, dim3(2048, 8), dim3(256), 0, stream, ca, ws);
  hipLaunchKernelGGL(proj_gemm, dim3(8, 64, 3), dim3(256), 0, stream, ws, ws, bq, bk, bv);
  hipLaunchKernelGGL(attn_fused, dim3(16, 64), dim3(128), 0, stream, ws, ws);
  hipLaunchKernelGGL(out_gemm, dim3(8, 64), dim3(256), 0, stream, ws, bo, out);
}

// Round 4
// 337.004 us; speedup vs baseline: 1.1384x; 1.0061x over previous
//
#include <hip/hip_runtime.h>
#include <hip/hip_bf16.h>
#include <stdint.h>

// Problem constants
#define NHEADS 16
#define SEQ    2048
#define DMODEL 1024
#define DK     64

// Workspace layout (offsets in bf16 elements)
#define QB_OFF  0ull          // 8192x1024 bf16 copy of Q   (reused as Ocomb after projections)
#define KB_OFF  8388608ull    // 8192x1024 bf16 copy of K
#define VB_OFF  16777216ull   // 8192x1024 bf16 copy of V
#define WQ_OFF  25165824ull   // 1024x1024
#define WK_OFF  26214400ull
#define WV_OFF  27262976ull
#define WO_OFF  28311552ull
#define QH_OFF  29360128ull   // (B,H,T,dk) bf16, pre-scaled by log2e/8
#define KH_OFF  37748736ull   // (B,H,T,dk) bf16
#define VT_OFF  46137344ull   // (B,H,dk,T) bf16, key order phi-permuted per 32-window, masked cols zeroed
#define MSKF_OFF 54525952ull  // (B,T) bf16 mask (0/1.0), phi-permuted per 32-window
#define OC_OFF  0ull          // combined attention output (B,T,DMODEL) bf16 (aliases QB)

typedef __attribute__((ext_vector_type(8))) __bf16 bf16x8;
typedef __attribute__((ext_vector_type(4))) float  floatx4;

__device__ __forceinline__ unsigned short f2bf(float f) {
  unsigned int u = __float_as_uint(f);
  u += 0x7fffu + ((u >> 16) & 1u);   // round-to-nearest-even
  return (unsigned short)(u >> 16);
}

// async global->LDS, 16B per lane. LDS dest must be wave-uniform base + lane*16B.
__device__ __forceinline__ void gld_lds16(const void* g, void* l) {
  __builtin_amdgcn_global_load_lds(
      (const __attribute__((address_space(1))) unsigned int*)(g),
      (__attribute__((address_space(3))) unsigned int*)(uintptr_t)(l),
      16, 0, 0);
}

// ---------------------------------------------------------------------------
// fp32 -> bf16 cast (Q,K,V + 4 weights) + mask int -> phi-permuted bf16 (0/1)
// ---------------------------------------------------------------------------
struct CastArgs {
  const float* src[8];
  unsigned long long off[8];
  unsigned int n[8];
};

__global__ __launch_bounds__(256) void cast_bf16(CastArgs a, unsigned short* __restrict__ ws) {
  int ti = blockIdx.y;
  unsigned int n = a.n[ti];
  unsigned int stride = gridDim.x * blockDim.x * 4u;
  unsigned int i0 = (blockIdx.x * blockDim.x + threadIdx.x) * 4u;
  if (ti == 7) {
    // mask ints -> bf16 0/1.0, permuted within each 32-token window to match
    // the V^T key order: pm[phi(g)] = mask[g], phi: b2->b3, b3->b4, b4->b2.
    const int* s = (const int*)a.src[7];
    unsigned short* d = ws + a.off[7];
    for (unsigned int i = i0; i < n; i += stride) {
      int4 v = *(const int4*)(s + i);
      ushort4 o;
      o.x = v.x ? 0x3f80u : 0u;
      o.y = v.y ? 0x3f80u : 0u;
      o.z = v.z ? 0x3f80u : 0u;
      o.w = v.w ? 0x3f80u : 0u;
      unsigned int p = (i & ~31u) | ((i & 12u) << 1) | ((i & 16u) >> 2) | (i & 3u);
      *(ushort4*)(d + p) = o;   // i is 4-aligned -> p is 4-aligned, 4 contiguous shorts
    }
    return;
  }
  const float* s = a.src[ti];
  unsigned short* d = ws + a.off[ti];
  for (unsigned int i = i0; i < n; i += stride) {
    float4 v = *(const float4*)(s + i);
    ushort4 o;
    o.x = f2bf(v.x); o.y = f2bf(v.y); o.z = f2bf(v.z); o.w = f2bf(v.w);
    *(ushort4*)(d + i) = o;
  }
}

// ---------------------------------------------------------------------------
// Shared GEMM core: C[128x128] += A[128xK] * B[128xK]^T  (BT layout, K=1024)
// ---------------------------------------------------------------------------
__device__ __forceinline__ void gemm_core_128(
    const unsigned short* __restrict__ A, const unsigned short* __restrict__ Bw,
    int m0, int n0, unsigned short* As, unsigned short* Bs, floatx4 acc[4][4])
{
  int tid = threadIdx.x;
  int lane = tid & 63, l16 = lane & 15, quad = lane >> 4;
  int wave = tid >> 6, wm = wave >> 1, wn = wave & 1;
  #pragma unroll 1
  for (int kt = 0; kt < 32; ++kt) {
    __syncthreads();
    #pragma unroll
    for (int rnd = 0; rnd < 2; ++rnd) {
      int e = tid * 8 + rnd * 2048;
      int row = e >> 5, col = e & 31;
      gld_lds16(A  + (size_t)(m0 + row) * 1024 + kt * 32 + col, As + e);
      gld_lds16(Bw + (size_t)(n0 + row) * 1024 + kt * 32 + col, Bs + e);
    }
    __syncthreads();
    bf16x8 af[4], bfr[4];
    #pragma unroll
    for (int f = 0; f < 4; ++f) {
      af[f]  = *(const bf16x8*)(As + (wm * 64 + f * 16 + l16) * 32 + quad * 8);
      bfr[f] = *(const bf16x8*)(Bs + (wn * 64 + f * 16 + l16) * 32 + quad * 8);
    }
    #pragma unroll
    for (int fm = 0; fm < 4; ++fm)
      #pragma unroll
      for (int fn = 0; fn < 4; ++fn)
        acc[fm][fn] = __builtin_amdgcn_mfma_f32_16x16x32_bf16(af[fm], bfr[fn], acc[fm][fn], 0, 0, 0);
  }
}

// ---------------------------------------------------------------------------
// Projections with LDS-transposed coalesced epilogues.
//  z=0: q = (X_Q Wq^T + bq) * (log2e/8) -> (B,H,T,dk)
//  z=1: k = X_K Wk^T + bk               -> (B,H,T,dk)
//  z=2: V^T: D[d'][t] = (Wv[d',:]·X_V[t,:] + bv[d']) * mask[b][t]
//       -> (B,H,dk,T), t phi-permuted per 32
// grid (8, 64, 3)
// R9: z<2 tile remap for XCD/L2 locality. HW dispatches flat = x + 8y round-
//     robin over 8 XCDs (512 blocks/z, 512%8==0 so z boundary preserves phase).
//     Old: xcd = n-tile -> each XCD streams ALL 16 MB of A through 4 MB L2.
//     New: xcd owns an 8-m-panel chunk (2 MB A) x all 8 n (2 MB B) = 4 MB
//     working set, A panels touched by exactly one XCD, 8x reuse of both.
//     z=2 keeps natural map (xcd = nt&7): each V-column single-XCD already.
// ---------------------------------------------------------------------------
__global__ __launch_bounds__(256) void proj_gemm(
    const unsigned short* __restrict__ wsc, unsigned short* __restrict__ ws,
    const float* __restrict__ bq, const float* __restrict__ bk, const float* __restrict__ bv)
{
  __shared__ unsigned short smem[17408];    // K-loop: As/Bs (8192); epilogue: C 128x136
  unsigned short* As = smem;
  unsigned short* Bs = smem + 4096;
  int z = blockIdx.z;
  int tid = threadIdx.x, lane = tid & 63, l16 = lane & 15, quad = lane >> 4;
  int wave = tid >> 6, wm = wave >> 1, wn = wave & 1;

  if (z < 2) {
    const unsigned short* A  = wsc + (z == 0 ? QB_OFF : KB_OFF);
    const unsigned short* Bw = wsc + (z == 0 ? WQ_OFF : WK_OFF);
    const float* bias = (z == 0) ? bq : bk;
    unsigned short* dst = ws + (z == 0 ? QH_OFF : KH_OFF);
    float scale = (z == 0) ? 0.18033688011111772f : 1.0f;  // (1/8)*log2(e) for q

    // XCD-locality remap (see header comment)
    int flat = blockIdx.y * 8 + blockIdx.x;   // [0,512), hw xcd = flat & 7
    int xcd = flat & 7, slot = flat >> 3;     // slot in [0,64)
    int m_t = xcd * 8 + (slot >> 3);          // m-tile [0,64)
    int n_t = slot & 7;                       // n-tile [0,8)
    int m0 = m_t * 128, n0 = n_t * 128;
    floatx4 acc[4][4] = {};
    gemm_core_128(A, Bw, m0, n0, As, Bs, acc);

    __syncthreads();   // all As/Bs reads done before C overwrite
    #pragma unroll
    for (int fn = 0; fn < 4; ++fn) {
      int c = wn * 64 + fn * 16 + l16;
      float bvv = bias[n0 + c];
      #pragma unroll
      for (int fm = 0; fm < 4; ++fm)
        #pragma unroll
        for (int r = 0; r < 4; ++r) {
          int t = wm * 64 + fm * 16 + quad * 4 + r;
          smem[t * 136 + c] = f2bf((acc[fm][fn][r] + bvv) * scale);
        }
    }
    __syncthreads();
    #pragma unroll
    for (int it = 0; it < 8; ++it) {
      int e = it * 2048 + tid * 8;
      int t = e >> 7, c = e & 127;
      uint4 val = *(const uint4*)(smem + t * 136 + c);
      int m = m0 + t, b = m >> 11, tg = m & 2047;
      int h = (n0 + c) >> 6, d = (n0 + c) & 63;
      *(uint4*)(dst + ((size_t)(b * NHEADS + h) * SEQ + tg) * DK + d) = val;
    }
  } else {
    // V^T: per batch b, M=1024 (d'), N=2048 (t)
    int flat = blockIdx.y * 8 + blockIdx.x;          // [0,512)
    int b = flat >> 7, rem = flat & 127;
    int mt = rem >> 4, nt = rem & 15;
    int m0 = mt * 128, n0 = nt * 128;
    const unsigned short* A  = wsc + WV_OFF;                                  // Wv rows d'
    const unsigned short* Bw = wsc + VB_OFF + (size_t)b * SEQ * DMODEL;       // X_V rows t
    unsigned short* dst = ws + VT_OFF;

    floatx4 acc[4][4] = {};
    gemm_core_128(A, Bw, m0, n0, As, Bs, acc);

    // permuted bf16 mask for this batch: pm[n0 + tp] is mask of the token
    // stored at permuted column tp
    const unsigned short* pm = wsc + MSKF_OFF + (size_t)b * SEQ;
    int tpl[4];
    float mv[4];
    #pragma unroll
    for (int fn = 0; fn < 4; ++fn) {
      int t = wn * 64 + fn * 16 + l16;   // local token col [0,128)
      int tp = (t & ~31) | ((t & 12) << 1) | ((t & 16) >> 2) | (t & 3);  // phi^-1
      tpl[fn] = tp;
      mv[fn] = __uint_as_float((unsigned int)pm[n0 + tp] << 16);
    }

    __syncthreads();
    #pragma unroll
    for (int fm = 0; fm < 4; ++fm) {
      int mb = m0 + wm * 64 + fm * 16 + quad * 4;
      float4 bb4 = *(const float4*)(bv + mb);
      float bbv[4] = {bb4.x, bb4.y, bb4.z, bb4.w};
      #pragma unroll
      for (int r = 0; r < 4; ++r) {
        int mrow = wm * 64 + fm * 16 + quad * 4 + r;
        #pragma unroll
        for (int fn = 0; fn < 4; ++fn)
          smem[mrow * 136 + tpl[fn]] = f2bf((acc[fm][fn][r] + bbv[r]) * mv[fn]);
      }
    }
    __syncthreads();
    #pragma unroll
    for (int it = 0; it < 8; ++it) {
      int e = it * 2048 + tid * 8;
      int mrow = e >> 7, tcol = e & 127;
      uint4 val = *(const uint4*)(smem + mrow * 136 + tcol);
      int m = m0 + mrow, h = m >> 6, d = m & 63;
      *(uint4*)(dst + ((size_t)(b * NHEADS + h) * DK + d) * SEQ + n0 + tcol) = val;
    }
  }
}

// ---------------------------------------------------------------------------
// Fused flash attention, S^T formulation, fixed-max softmax (log2-domain).
// 64 q per wave. block = 128 threads (2 waves), 128 q per block.
// grid (16, 64) = 1024 blocks = 4/CU.
// R8: single-buffer structure + XCD-locality swizzle (all 16 q-blocks of one
//     (b,h) on the same XCD -> K/V L2-resident).
// ---------------------------------------------------------------------------
__global__ __launch_bounds__(128, 2) void attn_fused(
    const unsigned short* __restrict__ wsc, unsigned short* __restrict__ ws)
{
  __shared__ unsigned short smem[16640];   // 33280 B
  unsigned short* Ks  = smem;              // 128 keys x 64 d (2 chunks 128x32) = 8192
  unsigned short* Vts = smem + 8192;       // 64 d x 128 keys (4 chunks 64x32)  = 8192
  unsigned short* MskB = smem + 16384;     // 128 bf16 mask (phi-permuted key order)

  // XCD-locality swizzle: blocks dispatch round-robin over 8 XCDs by flat id.
  // Give XCD x the 8 bh's [x*8, x*8+8) and all 16 qt of each.
  int fid = blockIdx.y * gridDim.x + blockIdx.x;   // [0,1024)
  int xcd = fid & 7, slot = fid >> 3;              // slot in [0,128)
  int bh = xcd * 8 + (slot >> 4);
  int qt = slot & 15;
  int b = bh >> 4, h = bh & 15;
  int tid = threadIdx.x, wave = tid >> 6, lane = tid & 63, l16 = lane & 15, quad = lane >> 4;
  int wq = wave * 64;

  const unsigned short* qh = wsc + QH_OFF + (size_t)bh * SEQ * DK;
  const unsigned short* kh = wsc + KH_OFF + (size_t)bh * SEQ * DK;
  const unsigned short* vt = wsc + VT_OFF + (size_t)bh * DK * SEQ;
  const unsigned short* pm = wsc + MSKF_OFF + (size_t)b * SEQ;

  // stage Q tile (128x64) into Ks region, read B-operand frags, then release
  #pragma unroll
  for (int kk = 0; kk < 2; ++kk)
    #pragma unroll
    for (int rnd = 0; rnd < 4; ++rnd) {
      int e = tid * 8 + rnd * 1024;
      int row = e >> 5, col = e & 31;
      gld_lds16(qh + (size_t)(qt * 128 + row) * DK + kk * 32 + col, Ks + kk * 4096 + e);
    }
  __syncthreads();
  bf16x8 qf[4][2];
  #pragma unroll
  for (int fq = 0; fq < 4; ++fq)
    #pragma unroll
    for (int kk = 0; kk < 2; ++kk)
      qf[fq][kk] = *(const bf16x8*)(Ks + kk * 4096 + (wq + fq * 16 + l16) * 32 + quad * 8);

  floatx4 o[4][4] = {};
  floatx4 osum[4] = {};          // denominator accumulators (mask-row MFMA)
  const floatx4 zero4 = {};

  #pragma unroll 1
  for (int jt = 0; jt < 16; ++jt) {
    __syncthreads();   // prior LDS reads (incl. Q frags on jt==0) complete
    #pragma unroll
    for (int kk = 0; kk < 2; ++kk)
      #pragma unroll
      for (int rnd = 0; rnd < 4; ++rnd) {
        int e = tid * 8 + rnd * 1024;
        int row = e >> 5, col = e & 31;
        gld_lds16(kh + (size_t)(jt * 128 + row) * DK + kk * 32 + col, Ks + kk * 4096 + e);
      }
    #pragma unroll
    for (int kk = 0; kk < 4; ++kk)
      #pragma unroll
      for (int rnd = 0; rnd < 2; ++rnd) {
        int e = tid * 8 + rnd * 1024;
        int row = e >> 5, col = e & 31;
        gld_lds16(vt + (size_t)row * SEQ + jt * 128 + kk * 32 + col, Vts + kk * 2048 + e);
      }
    if (tid < 16)
      gld_lds16(pm + jt * 128 + tid * 8, MskB + tid * 8);
    __syncthreads();

    // per-32-key chunk: S^T -> exp2 -> pack -> denom-MFMA -> PV
    #pragma unroll
    for (int w = 0; w < 4; ++w) {
      floatx4 s[2][4];
      #pragma unroll
      for (int f2 = 0; f2 < 2; ++f2) {
        int fk = 2 * w + f2;
        bf16x8 kf0 = *(const bf16x8*)(Ks +        (fk * 16 + l16) * 32 + quad * 8);
        bf16x8 kf1 = *(const bf16x8*)(Ks + 4096 + (fk * 16 + l16) * 32 + quad * 8);
        #pragma unroll
        for (int fq = 0; fq < 4; ++fq) {
          s[f2][fq] = __builtin_amdgcn_mfma_f32_16x16x32_bf16(kf0, qf[fq][0], zero4, 0, 0, 0);
          s[f2][fq] = __builtin_amdgcn_mfma_f32_16x16x32_bf16(kf1, qf[fq][1], s[f2][fq], 0, 0, 0);
        }
      }
      #pragma unroll
      for (int f2 = 0; f2 < 2; ++f2)
        #pragma unroll
        for (int fq = 0; fq < 4; ++fq)
          #pragma unroll
          for (int r = 0; r < 4; ++r)
            s[f2][fq][r] = __builtin_amdgcn_exp2f(s[f2][fq][r]);

      union { unsigned int u[4]; bf16x8 v; } pf[4];
      #pragma unroll
      for (int fq = 0; fq < 4; ++fq) {
        asm("v_cvt_pk_bf16_f32 %0, %1, %2" : "=v"(pf[fq].u[0]) : "v"(s[0][fq][0]), "v"(s[0][fq][1]));
        asm("v_cvt_pk_bf16_f32 %0, %1, %2" : "=v"(pf[fq].u[1]) : "v"(s[0][fq][2]), "v"(s[0][fq][3]));
        asm("v_cvt_pk_bf16_f32 %0, %1, %2" : "=v"(pf[fq].u[2]) : "v"(s[1][fq][0]), "v"(s[1][fq][1]));
        asm("v_cvt_pk_bf16_f32 %0, %1, %2" : "=v"(pf[fq].u[3]) : "v"(s[1][fq][2]), "v"(s[1][fq][3]));
      }

      // denominator: A = mask value in ALL 16 rows -> every C row holds
      // sum_k mask[k]*p[k][q]; broadcast LDS read (same addr for all l16)
      bf16x8 mvf = *(const bf16x8*)(MskB + w * 32 + quad * 8);
      #pragma unroll
      for (int fq = 0; fq < 4; ++fq)
        osum[fq] = __builtin_amdgcn_mfma_f32_16x16x32_bf16(mvf, pf[fq].v, osum[fq], 0, 0, 0);

      #pragma unroll
      for (int fd = 0; fd < 4; ++fd) {
        bf16x8 vf = *(const bf16x8*)(Vts + w * 2048 + (fd * 16 + l16) * 32 + quad * 8);
        #pragma unroll
        for (int fq = 0; fq < 4; ++fq)
          o[fd][fq] = __builtin_amdgcn_mfma_f32_16x16x32_bf16(vf, pf[fq].v, o[fd][fq], 0, 0, 0);
      }
    }
  }

  // every lane already holds its q's denominator (all osum rows identical)
  float inv[4];
  #pragma unroll
  for (int fq = 0; fq < 4; ++fq)
    inv[fq] = __builtin_amdgcn_rcpf(osum[fq][0]);

  __syncthreads();
  unsigned short* Ot = smem;   // 128 q x 72 (64 d + 8 pad)
  #pragma unroll
  for (int fd = 0; fd < 4; ++fd)
    #pragma unroll
    for (int fq = 0; fq < 4; ++fq)
      #pragma unroll
      for (int r = 0; r < 4; ++r) {
        int q = wq + fq * 16 + l16;
        int d = fd * 16 + quad * 4 + r;
        Ot[q * 72 + d] = f2bf(o[fd][fq][r] * inv[fq]);
      }
  __syncthreads();
  unsigned short* oc = ws + OC_OFF;
  #pragma unroll
  for (int rr = 0; rr < 8; ++rr) {
    int e = rr * 1024 + tid * 8;
    int q = e >> 6, off = e & 63;
    uint4 val = *(const uint4*)(Ot + q * 72 + off);
    *(uint4*)(oc + ((size_t)(b * SEQ + qt * 128 + q)) * DMODEL + h * DK + off) = val;
  }
}

// ---------------------------------------------------------------------------
// Output projection: out = Ocomb Wo^T + bo  (fp32 out)
// R9: same XCD-locality remap as proj_gemm z<2.
// ---------------------------------------------------------------------------
__global__ __launch_bounds__(256) void out_gemm(
    const unsigned short* __restrict__ wsc, const float* __restrict__ bo,
    float* __restrict__ out)
{
  __shared__ unsigned short smem[8192];
  unsigned short* As = smem;
  unsigned short* Bs = smem + 4096;
  int flat = blockIdx.y * 8 + blockIdx.x;   // [0,512), hw xcd = flat & 7
  int xcd = flat & 7, slot = flat >> 3;
  int m_t = xcd * 8 + (slot >> 3);
  int n_t = slot & 7;
  int m0 = m_t * 128, n0 = n_t * 128;
  floatx4 acc[4][4] = {};
  gemm_core_128(wsc + OC_OFF, wsc + WO_OFF, m0, n0, As, Bs, acc);

  int tid = threadIdx.x, lane = tid & 63, l16 = lane & 15, quad = lane >> 4;
  int wave = tid >> 6, wm = wave >> 1, wn = wave & 1;
  #pragma unroll
  for (int fn = 0; fn < 4; ++fn) {
    int n = n0 + wn * 64 + fn * 16 + l16;
    float bvv = bo[n];
    #pragma unroll
    for (int fm = 0; fm < 4; ++fm)
      #pragma unroll
      for (int r = 0; r < 4; ++r) {
        int m = m0 + wm * 64 + fm * 16 + quad * 4 + r;
        out[(size_t)m * DMODEL + n] = acc[fm][fn][r] + bvv;
      }
  }
}

// ---------------------------------------------------------------------------
extern "C" void kernel_launch(void* const* d_in, const int* in_sizes, int n_in,
                              void* d_out, int out_size, void* d_ws, size_t ws_size,
                              hipStream_t stream) {
  const float* Q    = (const float*)d_in[0];
  const float* K    = (const float*)d_in[1];
  const float* V    = (const float*)d_in[2];
  const float* bq   = (const float*)d_in[5];
  const float* bk   = (const float*)d_in[7];
  const float* bv   = (const float*)d_in[9];
  const float* bo   = (const float*)d_in[11];
  unsigned short* ws = (unsigned short*)d_ws;
  float* out = (float*)d_out;

  CastArgs ca;
  ca.src[0] = Q;  ca.src[1] = K;  ca.src[2] = V;
  ca.src[3] = (const float*)d_in[4]; ca.src[4] = (const float*)d_in[6];
  ca.src[5] = (const float*)d_in[8]; ca.src[6] = (const float*)d_in[10];
  ca.src[7] = (const float*)d_in[3];   // mask ints
  ca.off[0] = QB_OFF; ca.off[1] = KB_OFF; ca.off[2] = VB_OFF;
  ca.off[3] = WQ_OFF; ca.off[4] = WK_OFF; ca.off[5] = WV_OFF; ca.off[6] = WO_OFF;
  ca.off[7] = MSKF_OFF;
  ca.n[0] = ca.n[1] = ca.n[2] = 8388608u;
  ca.n[3] = ca.n[4] = ca.n[5] = ca.n[6] = 1048576u;
  ca.n[7] = 8192u;

  hipLaunchKernelGGL(cast_bf16, dim3(2048, 8), dim3(256), 0, stream, ca, ws);
  hipLaunchKernelGGL(proj_gemm, dim3(8, 64, 3), dim3(256), 0, stream, ws, ws, bq, bk, bv);
  hipLaunchKernelGGL(attn_fused, dim3(16, 64), dim3(128), 0, stream, ws, ws);
  hipLaunchKernelGGL(out_gemm, dim3(8, 64), dim3(256), 0, stream, ws, bo, out);
}

// Round 5
// 334.396 us; speedup vs baseline: 1.1473x; 1.0078x over previous
//
#include <hip/hip_runtime.h>
#include <hip/hip_bf16.h>
#include <stdint.h>

// Problem constants
#define NHEADS 16
#define SEQ    2048
#define DMODEL 1024
#define DK     64

// Workspace layout (offsets in bf16 elements)
#define QB_OFF  0ull          // 8192x1024 bf16 copy of Q   (reused as Ocomb after projections)
#define KB_OFF  8388608ull    // 8192x1024 bf16 copy of K
#define VB_OFF  16777216ull   // 8192x1024 bf16 copy of V
#define WQ_OFF  25165824ull   // 1024x1024
#define WK_OFF  26214400ull
#define WV_OFF  27262976ull
#define WO_OFF  28311552ull
#define QH_OFF  29360128ull   // (B,H,T,dk) bf16, pre-scaled by log2e/8
#define KH_OFF  37748736ull   // (B,H,T,dk) bf16
#define VT_OFF  46137344ull   // (B,H,dk,T) bf16, key order phi-permuted per 32-window, masked cols zeroed
#define MSKF_OFF 54525952ull  // (B,T) bf16 mask (0/1.0), phi-permuted per 32-window
#define OC_OFF  0ull          // combined attention output (B,T,DMODEL) bf16 (aliases QB)

typedef __attribute__((ext_vector_type(8))) __bf16 bf16x8;
typedef __attribute__((ext_vector_type(4))) float  floatx4;

__device__ __forceinline__ unsigned short f2bf(float f) {
  unsigned int u = __float_as_uint(f);
  u += 0x7fffu + ((u >> 16) & 1u);   // round-to-nearest-even
  return (unsigned short)(u >> 16);
}

// async global->LDS, 16B per lane. LDS dest must be wave-uniform base + lane*16B.
__device__ __forceinline__ void gld_lds16(const void* g, void* l) {
  __builtin_amdgcn_global_load_lds(
      (const __attribute__((address_space(1))) unsigned int*)(g),
      (__attribute__((address_space(3))) unsigned int*)(uintptr_t)(l),
      16, 0, 0);
}

// ---------------------------------------------------------------------------
// fp32 -> bf16 cast (Q,K,V + 4 weights) + mask int -> phi-permuted bf16 (0/1)
// ---------------------------------------------------------------------------
struct CastArgs {
  const float* src[8];
  unsigned long long off[8];
  unsigned int n[8];
};

__global__ __launch_bounds__(256) void cast_bf16(CastArgs a, unsigned short* __restrict__ ws) {
  int ti = blockIdx.y;
  unsigned int n = a.n[ti];
  unsigned int stride = gridDim.x * blockDim.x * 4u;
  unsigned int i0 = (blockIdx.x * blockDim.x + threadIdx.x) * 4u;
  if (ti == 7) {
    // mask ints -> bf16 0/1.0, permuted within each 32-token window to match
    // the V^T key order: pm[phi(g)] = mask[g], phi: b2->b3, b3->b4, b4->b2.
    const int* s = (const int*)a.src[7];
    unsigned short* d = ws + a.off[7];
    for (unsigned int i = i0; i < n; i += stride) {
      int4 v = *(const int4*)(s + i);
      ushort4 o;
      o.x = v.x ? 0x3f80u : 0u;
      o.y = v.y ? 0x3f80u : 0u;
      o.z = v.z ? 0x3f80u : 0u;
      o.w = v.w ? 0x3f80u : 0u;
      unsigned int p = (i & ~31u) | ((i & 12u) << 1) | ((i & 16u) >> 2) | (i & 3u);
      *(ushort4*)(d + p) = o;   // i is 4-aligned -> p is 4-aligned, 4 contiguous shorts
    }
    return;
  }
  const float* s = a.src[ti];
  unsigned short* d = ws + a.off[ti];
  for (unsigned int i = i0; i < n; i += stride) {
    float4 v = *(const float4*)(s + i);
    ushort4 o;
    o.x = f2bf(v.x); o.y = f2bf(v.y); o.z = f2bf(v.z); o.w = f2bf(v.w);
    *(ushort4*)(d + i) = o;
  }
}

// ---------------------------------------------------------------------------
// Shared GEMM core: C[128x128] += A[128xK] * B[128xK]^T  (BT layout, K=1024)
// ---------------------------------------------------------------------------
__device__ __forceinline__ void gemm_core_128(
    const unsigned short* __restrict__ A, const unsigned short* __restrict__ Bw,
    int m0, int n0, unsigned short* As, unsigned short* Bs, floatx4 acc[4][4])
{
  int tid = threadIdx.x;
  int lane = tid & 63, l16 = lane & 15, quad = lane >> 4;
  int wave = tid >> 6, wm = wave >> 1, wn = wave & 1;
  #pragma unroll 1
  for (int kt = 0; kt < 32; ++kt) {
    __syncthreads();
    #pragma unroll
    for (int rnd = 0; rnd < 2; ++rnd) {
      int e = tid * 8 + rnd * 2048;
      int row = e >> 5, col = e & 31;
      gld_lds16(A  + (size_t)(m0 + row) * 1024 + kt * 32 + col, As + e);
      gld_lds16(Bw + (size_t)(n0 + row) * 1024 + kt * 32 + col, Bs + e);
    }
    __syncthreads();
    bf16x8 af[4], bfr[4];
    #pragma unroll
    for (int f = 0; f < 4; ++f) {
      af[f]  = *(const bf16x8*)(As + (wm * 64 + f * 16 + l16) * 32 + quad * 8);
      bfr[f] = *(const bf16x8*)(Bs + (wn * 64 + f * 16 + l16) * 32 + quad * 8);
    }
    #pragma unroll
    for (int fm = 0; fm < 4; ++fm)
      #pragma unroll
      for (int fn = 0; fn < 4; ++fn)
        acc[fm][fn] = __builtin_amdgcn_mfma_f32_16x16x32_bf16(af[fm], bfr[fn], acc[fm][fn], 0, 0, 0);
  }
}

// ---------------------------------------------------------------------------
// Projections with LDS-transposed coalesced epilogues.
//  z=0: q = (X_Q Wq^T + bq) * (log2e/8) -> (B,H,T,dk)
//  z=1: k = X_K Wk^T + bk               -> (B,H,T,dk)
//  z=2: V^T: D[d'][t] = (Wv[d',:]·X_V[t,:] + bv[d']) * mask[b][t]
//       -> (B,H,dk,T), t phi-permuted per 32
// grid (8, 64, 3)
// R9: z<2 tile remap for XCD/L2 locality (xcd owns 8-m-panel chunk x all 8 n,
//     4 MB working set per XCD). z=2 keeps natural map.
// ---------------------------------------------------------------------------
__global__ __launch_bounds__(256) void proj_gemm(
    const unsigned short* __restrict__ wsc, unsigned short* __restrict__ ws,
    const float* __restrict__ bq, const float* __restrict__ bk, const float* __restrict__ bv)
{
  __shared__ unsigned short smem[17408];    // K-loop: As/Bs (8192); epilogue: C 128x136
  unsigned short* As = smem;
  unsigned short* Bs = smem + 4096;
  int z = blockIdx.z;
  int tid = threadIdx.x, lane = tid & 63, l16 = lane & 15, quad = lane >> 4;
  int wave = tid >> 6, wm = wave >> 1, wn = wave & 1;

  if (z < 2) {
    const unsigned short* A  = wsc + (z == 0 ? QB_OFF : KB_OFF);
    const unsigned short* Bw = wsc + (z == 0 ? WQ_OFF : WK_OFF);
    const float* bias = (z == 0) ? bq : bk;
    unsigned short* dst = ws + (z == 0 ? QH_OFF : KH_OFF);
    float scale = (z == 0) ? 0.18033688011111772f : 1.0f;  // (1/8)*log2(e) for q

    // XCD-locality remap (see header comment)
    int flat = blockIdx.y * 8 + blockIdx.x;   // [0,512), hw xcd = flat & 7
    int xcd = flat & 7, slot = flat >> 3;     // slot in [0,64)
    int m_t = xcd * 8 + (slot >> 3);          // m-tile [0,64)
    int n_t = slot & 7;                       // n-tile [0,8)
    int m0 = m_t * 128, n0 = n_t * 128;
    floatx4 acc[4][4] = {};
    gemm_core_128(A, Bw, m0, n0, As, Bs, acc);

    __syncthreads();   // all As/Bs reads done before C overwrite
    #pragma unroll
    for (int fn = 0; fn < 4; ++fn) {
      int c = wn * 64 + fn * 16 + l16;
      float bvv = bias[n0 + c];
      #pragma unroll
      for (int fm = 0; fm < 4; ++fm)
        #pragma unroll
        for (int r = 0; r < 4; ++r) {
          int t = wm * 64 + fm * 16 + quad * 4 + r;
          smem[t * 136 + c] = f2bf((acc[fm][fn][r] + bvv) * scale);
        }
    }
    __syncthreads();
    #pragma unroll
    for (int it = 0; it < 8; ++it) {
      int e = it * 2048 + tid * 8;
      int t = e >> 7, c = e & 127;
      uint4 val = *(const uint4*)(smem + t * 136 + c);
      int m = m0 + t, b = m >> 11, tg = m & 2047;
      int h = (n0 + c) >> 6, d = (n0 + c) & 63;
      *(uint4*)(dst + ((size_t)(b * NHEADS + h) * SEQ + tg) * DK + d) = val;
    }
  } else {
    // V^T: per batch b, M=1024 (d'), N=2048 (t)
    int flat = blockIdx.y * 8 + blockIdx.x;          // [0,512)
    int b = flat >> 7, rem = flat & 127;
    int mt = rem >> 4, nt = rem & 15;
    int m0 = mt * 128, n0 = nt * 128;
    const unsigned short* A  = wsc + WV_OFF;                                  // Wv rows d'
    const unsigned short* Bw = wsc + VB_OFF + (size_t)b * SEQ * DMODEL;       // X_V rows t
    unsigned short* dst = ws + VT_OFF;

    floatx4 acc[4][4] = {};
    gemm_core_128(A, Bw, m0, n0, As, Bs, acc);

    // permuted bf16 mask for this batch: pm[n0 + tp] is mask of the token
    // stored at permuted column tp
    const unsigned short* pm = wsc + MSKF_OFF + (size_t)b * SEQ;
    int tpl[4];
    float mv[4];
    #pragma unroll
    for (int fn = 0; fn < 4; ++fn) {
      int t = wn * 64 + fn * 16 + l16;   // local token col [0,128)
      int tp = (t & ~31) | ((t & 12) << 1) | ((t & 16) >> 2) | (t & 3);  // phi^-1
      tpl[fn] = tp;
      mv[fn] = __uint_as_float((unsigned int)pm[n0 + tp] << 16);
    }

    __syncthreads();
    #pragma unroll
    for (int fm = 0; fm < 4; ++fm) {
      int mb = m0 + wm * 64 + fm * 16 + quad * 4;
      float4 bb4 = *(const float4*)(bv + mb);
      float bbv[4] = {bb4.x, bb4.y, bb4.z, bb4.w};
      #pragma unroll
      for (int r = 0; r < 4; ++r) {
        int mrow = wm * 64 + fm * 16 + quad * 4 + r;
        #pragma unroll
        for (int fn = 0; fn < 4; ++fn)
          smem[mrow * 136 + tpl[fn]] = f2bf((acc[fm][fn][r] + bbv[r]) * mv[fn]);
      }
    }
    __syncthreads();
    #pragma unroll
    for (int it = 0; it < 8; ++it) {
      int e = it * 2048 + tid * 8;
      int mrow = e >> 7, tcol = e & 127;
      uint4 val = *(const uint4*)(smem + mrow * 136 + tcol);
      int m = m0 + mrow, h = m >> 6, d = m & 63;
      *(uint4*)(dst + ((size_t)(b * NHEADS + h) * DK + d) * SEQ + n0 + tcol) = val;
    }
  }
}

// ---------------------------------------------------------------------------
// Fused flash attention, S^T formulation, fixed-max softmax (log2-domain).
// 64 q per wave. block = 128 threads (2 waves), 128 q per block.
// grid (16, 64) = 1024 blocks = 4/CU. XCD-locality swizzle (R8).
// R10: two-phase pipeline on the SAME two barriers/jt, so each vmcnt(0)
//      drain is covered by a compute phase (R9 showed latency-bound, not
//      fetch-bound):
//        A: issue V(jt) -> QK+exp2+pack+osum (covers V latency) -> sync
//        B: issue K(jt+1)+mask -> setprio(1) PV MFMA cluster (covers K
//           latency) -> sync
//      pf fragments for all 4 w persist across phases (+64 VGPR, <256 cap).
// ---------------------------------------------------------------------------
__global__ __launch_bounds__(128, 2) void attn_fused(
    const unsigned short* __restrict__ wsc, unsigned short* __restrict__ ws)
{
  __shared__ unsigned short smem[16640];   // 33280 B
  unsigned short* Ks  = smem;              // 128 keys x 64 d (2 chunks 128x32) = 8192
  unsigned short* Vts = smem + 8192;       // 64 d x 128 keys (4 chunks 64x32)  = 8192
  unsigned short* MskB = smem + 16384;     // 128 bf16 mask (phi-permuted key order)

  // XCD-locality swizzle: blocks dispatch round-robin over 8 XCDs by flat id.
  // Give XCD x the 8 bh's [x*8, x*8+8) and all 16 qt of each.
  int fid = blockIdx.y * gridDim.x + blockIdx.x;   // [0,1024)
  int xcd = fid & 7, slot = fid >> 3;              // slot in [0,128)
  int bh = xcd * 8 + (slot >> 4);
  int qt = slot & 15;
  int b = bh >> 4, h = bh & 15;
  int tid = threadIdx.x, wave = tid >> 6, lane = tid & 63, l16 = lane & 15, quad = lane >> 4;
  int wq = wave * 64;

  const unsigned short* qh = wsc + QH_OFF + (size_t)bh * SEQ * DK;
  const unsigned short* kh = wsc + KH_OFF + (size_t)bh * SEQ * DK;
  const unsigned short* vt = wsc + VT_OFF + (size_t)bh * DK * SEQ;
  const unsigned short* pm = wsc + MSKF_OFF + (size_t)b * SEQ;

  // stage Q tile (128x64) into Ks region, read B-operand frags, then release
  #pragma unroll
  for (int kk = 0; kk < 2; ++kk)
    #pragma unroll
    for (int rnd = 0; rnd < 4; ++rnd) {
      int e = tid * 8 + rnd * 1024;
      int row = e >> 5, col = e & 31;
      gld_lds16(qh + (size_t)(qt * 128 + row) * DK + kk * 32 + col, Ks + kk * 4096 + e);
    }
  __syncthreads();
  bf16x8 qf[4][2];
  #pragma unroll
  for (int fq = 0; fq < 4; ++fq)
    #pragma unroll
    for (int kk = 0; kk < 2; ++kk)
      qf[fq][kk] = *(const bf16x8*)(Ks + kk * 4096 + (wq + fq * 16 + l16) * 32 + quad * 8);
  __syncthreads();   // all Q reads done before K(0) staging overwrites Ks

  // prologue: stage K(0) + mask(0) (only drain not covered by compute)
  #pragma unroll
  for (int kk = 0; kk < 2; ++kk)
    #pragma unroll
    for (int rnd = 0; rnd < 4; ++rnd) {
      int e = tid * 8 + rnd * 1024;
      int row = e >> 5, col = e & 31;
      gld_lds16(kh + (size_t)row * DK + kk * 32 + col, Ks + kk * 4096 + e);
    }
  if (tid < 16)
    gld_lds16(pm + tid * 8, MskB + tid * 8);
  __syncthreads();   // K(0)/mask(0) ready

  floatx4 o[4][4] = {};
  floatx4 osum[4] = {};          // denominator accumulators (mask-row MFMA)
  const floatx4 zero4 = {};

  union PU { unsigned int u[4][4]; bf16x8 v[4]; };   // [fq] x 4 dwords each

  #pragma unroll 1
  for (int jt = 0; jt < 16; ++jt) {
    // ---- Phase A: issue V(jt); QK^T + exp2 + pack + osum from Ks/MskB ----
    #pragma unroll
    for (int kk = 0; kk < 4; ++kk)
      #pragma unroll
      for (int rnd = 0; rnd < 2; ++rnd) {
        int e = tid * 8 + rnd * 1024;
        int row = e >> 5, col = e & 31;
        gld_lds16(vt + (size_t)row * SEQ + jt * 128 + kk * 32 + col, Vts + kk * 2048 + e);
      }

    PU pf[4];   // persists into Phase B
    #pragma unroll
    for (int w = 0; w < 4; ++w) {
      floatx4 s[2][4];
      #pragma unroll
      for (int f2 = 0; f2 < 2; ++f2) {
        int fk = 2 * w + f2;
        bf16x8 kf0 = *(const bf16x8*)(Ks +        (fk * 16 + l16) * 32 + quad * 8);
        bf16x8 kf1 = *(const bf16x8*)(Ks + 4096 + (fk * 16 + l16) * 32 + quad * 8);
        #pragma unroll
        for (int fq = 0; fq < 4; ++fq) {
          s[f2][fq] = __builtin_amdgcn_mfma_f32_16x16x32_bf16(kf0, qf[fq][0], zero4, 0, 0, 0);
          s[f2][fq] = __builtin_amdgcn_mfma_f32_16x16x32_bf16(kf1, qf[fq][1], s[f2][fq], 0, 0, 0);
        }
      }
      #pragma unroll
      for (int f2 = 0; f2 < 2; ++f2)
        #pragma unroll
        for (int fq = 0; fq < 4; ++fq)
          #pragma unroll
          for (int r = 0; r < 4; ++r)
            s[f2][fq][r] = __builtin_amdgcn_exp2f(s[f2][fq][r]);

      #pragma unroll
      for (int fq = 0; fq < 4; ++fq) {
        asm("v_cvt_pk_bf16_f32 %0, %1, %2" : "=v"(pf[w].u[fq][0]) : "v"(s[0][fq][0]), "v"(s[0][fq][1]));
        asm("v_cvt_pk_bf16_f32 %0, %1, %2" : "=v"(pf[w].u[fq][1]) : "v"(s[0][fq][2]), "v"(s[0][fq][3]));
        asm("v_cvt_pk_bf16_f32 %0, %1, %2" : "=v"(pf[w].u[fq][2]) : "v"(s[1][fq][0]), "v"(s[1][fq][1]));
        asm("v_cvt_pk_bf16_f32 %0, %1, %2" : "=v"(pf[w].u[fq][3]) : "v"(s[1][fq][2]), "v"(s[1][fq][3]));
      }

      // denominator: A = mask value in ALL 16 rows -> every C row holds
      // sum_k mask[k]*p[k][q]; broadcast LDS read (same addr for all l16)
      bf16x8 mvf = *(const bf16x8*)(MskB + w * 32 + quad * 8);
      #pragma unroll
      for (int fq = 0; fq < 4; ++fq)
        osum[fq] = __builtin_amdgcn_mfma_f32_16x16x32_bf16(mvf, pf[w].v[fq], osum[fq], 0, 0, 0);
    }

    __syncthreads();   // V(jt) landed (vmcnt, hidden under A); Ks/MskB reads done

    // ---- Phase B: issue K(jt+1)+mask; pure-PV MFMA cluster ----
    if (jt < 15) {
      const unsigned short* khn = kh + (size_t)(jt + 1) * 128 * DK;
      #pragma unroll
      for (int kk = 0; kk < 2; ++kk)
        #pragma unroll
        for (int rnd = 0; rnd < 4; ++rnd) {
          int e = tid * 8 + rnd * 1024;
          int row = e >> 5, col = e & 31;
          gld_lds16(khn + (size_t)row * DK + kk * 32 + col, Ks + kk * 4096 + e);
        }
      if (tid < 16)
        gld_lds16(pm + (jt + 1) * 128 + tid * 8, MskB + tid * 8);
    }

    __builtin_amdgcn_s_setprio(1);
    #pragma unroll
    for (int w = 0; w < 4; ++w)
      #pragma unroll
      for (int fd = 0; fd < 4; ++fd) {
        bf16x8 vf = *(const bf16x8*)(Vts + w * 2048 + (fd * 16 + l16) * 32 + quad * 8);
        #pragma unroll
        for (int fq = 0; fq < 4; ++fq)
          o[fd][fq] = __builtin_amdgcn_mfma_f32_16x16x32_bf16(vf, pf[w].v[fq], o[fd][fq], 0, 0, 0);
      }
    __builtin_amdgcn_s_setprio(0);

    __syncthreads();   // K(jt+1) landed (hidden under PV); Vts reads done
  }

  // every lane already holds its q's denominator (all osum rows identical)
  float inv[4];
  #pragma unroll
  for (int fq = 0; fq < 4; ++fq)
    inv[fq] = __builtin_amdgcn_rcpf(osum[fq][0]);

  unsigned short* Ot = smem;   // 128 q x 72 (64 d + 8 pad)
  #pragma unroll
  for (int fd = 0; fd < 4; ++fd)
    #pragma unroll
    for (int fq = 0; fq < 4; ++fq)
      #pragma unroll
      for (int r = 0; r < 4; ++r) {
        int q = wq + fq * 16 + l16;
        int d = fd * 16 + quad * 4 + r;
        Ot[q * 72 + d] = f2bf(o[fd][fq][r] * inv[fq]);
      }
  __syncthreads();
  unsigned short* oc = ws + OC_OFF;
  #pragma unroll
  for (int rr = 0; rr < 8; ++rr) {
    int e = rr * 1024 + tid * 8;
    int q = e >> 6, off = e & 63;
    uint4 val = *(const uint4*)(Ot + q * 72 + off);
    *(uint4*)(oc + ((size_t)(b * SEQ + qt * 128 + q)) * DMODEL + h * DK + off) = val;
  }
}

// ---------------------------------------------------------------------------
// Output projection: out = Ocomb Wo^T + bo  (fp32 out)
// R9: same XCD-locality remap as proj_gemm z<2.
// ---------------------------------------------------------------------------
__global__ __launch_bounds__(256) void out_gemm(
    const unsigned short* __restrict__ wsc, const float* __restrict__ bo,
    float* __restrict__ out)
{
  __shared__ unsigned short smem[8192];
  unsigned short* As = smem;
  unsigned short* Bs = smem + 4096;
  int flat = blockIdx.y * 8 + blockIdx.x;   // [0,512), hw xcd = flat & 7
  int xcd = flat & 7, slot = flat >> 3;
  int m_t = xcd * 8 + (slot >> 3);
  int n_t = slot & 7;
  int m0 = m_t * 128, n0 = n_t * 128;
  floatx4 acc[4][4] = {};
  gemm_core_128(wsc + OC_OFF, wsc + WO_OFF, m0, n0, As, Bs, acc);

  int tid = threadIdx.x, lane = tid & 63, l16 = lane & 15, quad = lane >> 4;
  int wave = tid >> 6, wm = wave >> 1, wn = wave & 1;
  #pragma unroll
  for (int fn = 0; fn < 4; ++fn) {
    int n = n0 + wn * 64 + fn * 16 + l16;
    float bvv = bo[n];
    #pragma unroll
    for (int fm = 0; fm < 4; ++fm)
      #pragma unroll
      for (int r = 0; r < 4; ++r) {
        int m = m0 + wm * 64 + fm * 16 + quad * 4 + r;
        out[(size_t)m * DMODEL + n] = acc[fm][fn][r] + bvv;
      }
  }
}

// ---------------------------------------------------------------------------
extern "C" void kernel_launch(void* const* d_in, const int* in_sizes, int n_in,
                              void* d_out, int out_size, void* d_ws, size_t ws_size,
                              hipStream_t stream) {
  const float* Q    = (const float*)d_in[0];
  const float* K    = (const float*)d_in[1];
  const float* V    = (const float*)d_in[2];
  const float* bq   = (const float*)d_in[5];
  const float* bk   = (const float*)d_in[7];
  const float* bv   = (const float*)d_in[9];
  const float* bo   = (const float*)d_in[11];
  unsigned short* ws = (unsigned short*)d_ws;
  float* out = (float*)d_out;

  CastArgs ca;
  ca.src[0] = Q;  ca.src[1] = K;  ca.src[2] = V;
  ca.src[3] = (const float*)d_in[4]; ca.src[4] = (const float*)d_in[6];
  ca.src[5] = (const float*)d_in[8]; ca.src[6] = (const float*)d_in[10];
  ca.src[7] = (const float*)d_in[3];   // mask ints
  ca.off[0] = QB_OFF; ca.off[1] = KB_OFF; ca.off[2] = VB_OFF;
  ca.off[3] = WQ_OFF; ca.off[4] = WK_OFF; ca.off[5] = WV_OFF; ca.off[6] = WO_OFF;
  ca.off[7] = MSKF_OFF;
  ca.n[0] = ca.n[1] = ca.n[2] = 8388608u;
  ca.n[3] = ca.n[4] = ca.n[5] = ca.n[6] = 1048576u;
  ca.n[7] = 8192u;

  hipLaunchKernelGGL(cast_bf16, dim3(2048, 8), dim3(256), 0, stream, ca, ws);
  hipLaunchKernelGGL(proj_gemm, dim3(8, 64, 3), dim3(256), 0, stream, ws, ws, bq, bk, bv);
  hipLaunchKernelGGL(attn_fused, dim3(16, 64), dim3(128), 0, stream, ws, ws);
  hipLaunchKernelGGL(out_gemm, dim3(8, 64), dim3(256), 0, stream, ws, bo, out);
}

// Round 6
// 311.697 us; speedup vs baseline: 1.2309x; 1.0728x over previous
//
#include <hip/hip_runtime.h>
#include <hip/hip_bf16.h>
#include <stdint.h>

// Problem constants
#define NHEADS 16
#define SEQ    2048
#define DMODEL 1024
#define DK     64

// Workspace layout (offsets in bf16 elements)
#define QB_OFF  0ull          // 8192x1024 bf16 copy of Q   (reused as Ocomb after projections)
#define KB_OFF  8388608ull    // 8192x1024 bf16 copy of K
#define VB_OFF  16777216ull   // 8192x1024 bf16 copy of V
#define WQ_OFF  25165824ull   // 1024x1024
#define WK_OFF  26214400ull
#define WV_OFF  27262976ull
#define WO_OFF  28311552ull
#define QH_OFF  29360128ull   // (B,H,T,dk) bf16, pre-scaled by log2e/8
#define KH_OFF  37748736ull   // (B,H,T,dk) bf16
#define VT_OFF  46137344ull   // (B,H,dk,T) bf16, key order phi-permuted per 32-window, masked cols zeroed
#define MSKF_OFF 54525952ull  // (B,T) bf16 mask (0/1.0), phi-permuted per 32-window
#define OC_OFF  0ull          // combined attention output (B,T,DMODEL) bf16 (aliases QB)

typedef __attribute__((ext_vector_type(8))) __bf16 bf16x8;
typedef __attribute__((ext_vector_type(4))) float  floatx4;

__device__ __forceinline__ unsigned short f2bf(float f) {
  unsigned int u = __float_as_uint(f);
  u += 0x7fffu + ((u >> 16) & 1u);   // round-to-nearest-even
  return (unsigned short)(u >> 16);
}

// async global->LDS, 16B per lane. LDS dest must be wave-uniform base + lane*16B.
__device__ __forceinline__ void gld_lds16(const void* g, void* l) {
  __builtin_amdgcn_global_load_lds(
      (const __attribute__((address_space(1))) unsigned int*)(g),
      (__attribute__((address_space(3))) unsigned int*)(uintptr_t)(l),
      16, 0, 0);
}

// ---------------------------------------------------------------------------
// fp32 -> bf16 cast (Q,K,V + 4 weights) + mask int -> phi-permuted bf16 (0/1)
// ---------------------------------------------------------------------------
struct CastArgs {
  const float* src[8];
  unsigned long long off[8];
  unsigned int n[8];
};

__global__ __launch_bounds__(256) void cast_bf16(CastArgs a, unsigned short* __restrict__ ws) {
  int ti = blockIdx.y;
  unsigned int n = a.n[ti];
  unsigned int stride = gridDim.x * blockDim.x * 4u;
  unsigned int i0 = (blockIdx.x * blockDim.x + threadIdx.x) * 4u;
  if (ti == 7) {
    // mask ints -> bf16 0/1.0, permuted within each 32-token window to match
    // the V^T key order: pm[phi(g)] = mask[g], phi: b2->b3, b3->b4, b4->b2.
    const int* s = (const int*)a.src[7];
    unsigned short* d = ws + a.off[7];
    for (unsigned int i = i0; i < n; i += stride) {
      int4 v = *(const int4*)(s + i);
      ushort4 o;
      o.x = v.x ? 0x3f80u : 0u;
      o.y = v.y ? 0x3f80u : 0u;
      o.z = v.z ? 0x3f80u : 0u;
      o.w = v.w ? 0x3f80u : 0u;
      unsigned int p = (i & ~31u) | ((i & 12u) << 1) | ((i & 16u) >> 2) | (i & 3u);
      *(ushort4*)(d + p) = o;   // i is 4-aligned -> p is 4-aligned, 4 contiguous shorts
    }
    return;
  }
  const float* s = a.src[ti];
  unsigned short* d = ws + a.off[ti];
  for (unsigned int i = i0; i < n; i += stride) {
    float4 v = *(const float4*)(s + i);
    ushort4 o;
    o.x = f2bf(v.x); o.y = f2bf(v.y); o.z = f2bf(v.z); o.w = f2bf(v.w);
    *(ushort4*)(d + i) = o;
  }
}

// ---------------------------------------------------------------------------
// Shared GEMM core: C[128x128] += A[128xK] * B[128xK]^T  (BT layout, K=1024)
// R11: LDS double-buffered K-loop. Per kt: issue stage(kt+1) -> ds_read +
//      MFMA(kt) (covers the L2-hit latency of the prefetch) -> ONE barrier
//      (vmcnt(0) drain lands after compute). 33 barriers vs 64. setprio(1)
//      around the MFMA cluster (phase-split exists now -> T5 applies).
//      sm must hold 16384 shorts (2 x (As 4096 + Bs 4096)).
// ---------------------------------------------------------------------------
__device__ __forceinline__ void gemm_core_128(
    const unsigned short* __restrict__ A, const unsigned short* __restrict__ Bw,
    int m0, int n0, unsigned short* sm, floatx4 acc[4][4])
{
  int tid = threadIdx.x;
  int lane = tid & 63, l16 = lane & 15, quad = lane >> 4;
  int wave = tid >> 6, wm = wave >> 1, wn = wave & 1;

  // prologue: stage kt=0 into buffer 0
  #pragma unroll
  for (int rnd = 0; rnd < 2; ++rnd) {
    int e = tid * 8 + rnd * 2048;
    int row = e >> 5, col = e & 31;
    gld_lds16(A  + (size_t)(m0 + row) * 1024 + col, sm + e);
    gld_lds16(Bw + (size_t)(n0 + row) * 1024 + col, sm + 4096 + e);
  }
  __syncthreads();   // buf0 ready

  int cur = 0;
  #pragma unroll 1
  for (int kt = 0; kt < 32; ++kt) {
    const unsigned short* As = sm + cur * 8192;
    const unsigned short* Bs = As + 4096;

    // prefetch kt+1 into the other buffer; stays in flight through compute
    if (kt < 31) {
      unsigned short* An = sm + (cur ^ 1) * 8192;
      #pragma unroll
      for (int rnd = 0; rnd < 2; ++rnd) {
        int e = tid * 8 + rnd * 2048;
        int row = e >> 5, col = e & 31;
        gld_lds16(A  + (size_t)(m0 + row) * 1024 + (kt + 1) * 32 + col, An + e);
        gld_lds16(Bw + (size_t)(n0 + row) * 1024 + (kt + 1) * 32 + col, An + 4096 + e);
      }
    }

    bf16x8 af[4], bfr[4];
    #pragma unroll
    for (int f = 0; f < 4; ++f) {
      af[f]  = *(const bf16x8*)(As + (wm * 64 + f * 16 + l16) * 32 + quad * 8);
      bfr[f] = *(const bf16x8*)(Bs + (wn * 64 + f * 16 + l16) * 32 + quad * 8);
    }
    __builtin_amdgcn_s_setprio(1);
    #pragma unroll
    for (int fm = 0; fm < 4; ++fm)
      #pragma unroll
      for (int fn = 0; fn < 4; ++fn)
        acc[fm][fn] = __builtin_amdgcn_mfma_f32_16x16x32_bf16(af[fm], bfr[fn], acc[fm][fn], 0, 0, 0);
    __builtin_amdgcn_s_setprio(0);

    __syncthreads();   // prefetch landed (vmcnt) + all reads of cur done
    cur ^= 1;
  }
}

// ---------------------------------------------------------------------------
// Projections with LDS-transposed coalesced epilogues.
//  z=0: q = (X_Q Wq^T + bq) * (log2e/8) -> (B,H,T,dk)
//  z=1: k = X_K Wk^T + bk               -> (B,H,T,dk)
//  z=2: V^T: D[d'][t] = (Wv[d',:]·X_V[t,:] + bv[d']) * mask[b][t]
//       -> (B,H,dk,T), t phi-permuted per 32
// grid (8, 64, 3)
// R9: z<2 tile remap for XCD/L2 locality (xcd owns 8-m-panel chunk x all 8 n,
//     4 MB working set per XCD). z=2 keeps natural map.
// ---------------------------------------------------------------------------
__global__ __launch_bounds__(256) void proj_gemm(
    const unsigned short* __restrict__ wsc, unsigned short* __restrict__ ws,
    const float* __restrict__ bq, const float* __restrict__ bk, const float* __restrict__ bv)
{
  __shared__ unsigned short smem[17408];    // K-loop dbuf: 16384; epilogue: C 128x136
  int z = blockIdx.z;
  int tid = threadIdx.x, lane = tid & 63, l16 = lane & 15, quad = lane >> 4;
  int wave = tid >> 6, wm = wave >> 1, wn = wave & 1;

  if (z < 2) {
    const unsigned short* A  = wsc + (z == 0 ? QB_OFF : KB_OFF);
    const unsigned short* Bw = wsc + (z == 0 ? WQ_OFF : WK_OFF);
    const float* bias = (z == 0) ? bq : bk;
    unsigned short* dst = ws + (z == 0 ? QH_OFF : KH_OFF);
    float scale = (z == 0) ? 0.18033688011111772f : 1.0f;  // (1/8)*log2(e) for q

    // XCD-locality remap (see header comment)
    int flat = blockIdx.y * 8 + blockIdx.x;   // [0,512), hw xcd = flat & 7
    int xcd = flat & 7, slot = flat >> 3;     // slot in [0,64)
    int m_t = xcd * 8 + (slot >> 3);          // m-tile [0,64)
    int n_t = slot & 7;                       // n-tile [0,8)
    int m0 = m_t * 128, n0 = n_t * 128;
    floatx4 acc[4][4] = {};
    gemm_core_128(A, Bw, m0, n0, smem, acc);

    __syncthreads();   // all LDS reads done before C overwrite
    #pragma unroll
    for (int fn = 0; fn < 4; ++fn) {
      int c = wn * 64 + fn * 16 + l16;
      float bvv = bias[n0 + c];
      #pragma unroll
      for (int fm = 0; fm < 4; ++fm)
        #pragma unroll
        for (int r = 0; r < 4; ++r) {
          int t = wm * 64 + fm * 16 + quad * 4 + r;
          smem[t * 136 + c] = f2bf((acc[fm][fn][r] + bvv) * scale);
        }
    }
    __syncthreads();
    #pragma unroll
    for (int it = 0; it < 8; ++it) {
      int e = it * 2048 + tid * 8;
      int t = e >> 7, c = e & 127;
      uint4 val = *(const uint4*)(smem + t * 136 + c);
      int m = m0 + t, b = m >> 11, tg = m & 2047;
      int h = (n0 + c) >> 6, d = (n0 + c) & 63;
      *(uint4*)(dst + ((size_t)(b * NHEADS + h) * SEQ + tg) * DK + d) = val;
    }
  } else {
    // V^T: per batch b, M=1024 (d'), N=2048 (t)
    int flat = blockIdx.y * 8 + blockIdx.x;          // [0,512)
    int b = flat >> 7, rem = flat & 127;
    int mt = rem >> 4, nt = rem & 15;
    int m0 = mt * 128, n0 = nt * 128;
    const unsigned short* A  = wsc + WV_OFF;                                  // Wv rows d'
    const unsigned short* Bw = wsc + VB_OFF + (size_t)b * SEQ * DMODEL;       // X_V rows t
    unsigned short* dst = ws + VT_OFF;

    floatx4 acc[4][4] = {};
    gemm_core_128(A, Bw, m0, n0, smem, acc);

    // permuted bf16 mask for this batch: pm[n0 + tp] is mask of the token
    // stored at permuted column tp
    const unsigned short* pm = wsc + MSKF_OFF + (size_t)b * SEQ;
    int tpl[4];
    float mv[4];
    #pragma unroll
    for (int fn = 0; fn < 4; ++fn) {
      int t = wn * 64 + fn * 16 + l16;   // local token col [0,128)
      int tp = (t & ~31) | ((t & 12) << 1) | ((t & 16) >> 2) | (t & 3);  // phi^-1
      tpl[fn] = tp;
      mv[fn] = __uint_as_float((unsigned int)pm[n0 + tp] << 16);
    }

    __syncthreads();
    #pragma unroll
    for (int fm = 0; fm < 4; ++fm) {
      int mb = m0 + wm * 64 + fm * 16 + quad * 4;
      float4 bb4 = *(const float4*)(bv + mb);
      float bbv[4] = {bb4.x, bb4.y, bb4.z, bb4.w};
      #pragma unroll
      for (int r = 0; r < 4; ++r) {
        int mrow = wm * 64 + fm * 16 + quad * 4 + r;
        #pragma unroll
        for (int fn = 0; fn < 4; ++fn)
          smem[mrow * 136 + tpl[fn]] = f2bf((acc[fm][fn][r] + bbv[r]) * mv[fn]);
      }
    }
    __syncthreads();
    #pragma unroll
    for (int it = 0; it < 8; ++it) {
      int e = it * 2048 + tid * 8;
      int mrow = e >> 7, tcol = e & 127;
      uint4 val = *(const uint4*)(smem + mrow * 136 + tcol);
      int m = m0 + mrow, h = m >> 6, d = m & 63;
      *(uint4*)(dst + ((size_t)(b * NHEADS + h) * DK + d) * SEQ + n0 + tcol) = val;
    }
  }
}

// ---------------------------------------------------------------------------
// Fused flash attention, S^T formulation, fixed-max softmax (log2-domain).
// 64 q per wave. block = 128 threads (2 waves), 128 q per block.
// grid (16, 64) = 1024 blocks = 4/CU. XCD-locality swizzle (R8).
// R10: two-phase pipeline on the SAME two barriers/jt, so each vmcnt(0)
//      drain is covered by a compute phase:
//        A: issue V(jt) -> QK+exp2+pack+osum (covers V latency) -> sync
//        B: issue K(jt+1)+mask -> setprio(1) PV MFMA cluster (covers K
//           latency) -> sync
// ---------------------------------------------------------------------------
__global__ __launch_bounds__(128, 2) void attn_fused(
    const unsigned short* __restrict__ wsc, unsigned short* __restrict__ ws)
{
  __shared__ unsigned short smem[16640];   // 33280 B
  unsigned short* Ks  = smem;              // 128 keys x 64 d (2 chunks 128x32) = 8192
  unsigned short* Vts = smem + 8192;       // 64 d x 128 keys (4 chunks 64x32)  = 8192
  unsigned short* MskB = smem + 16384;     // 128 bf16 mask (phi-permuted key order)

  // XCD-locality swizzle: blocks dispatch round-robin over 8 XCDs by flat id.
  // Give XCD x the 8 bh's [x*8, x*8+8) and all 16 qt of each.
  int fid = blockIdx.y * gridDim.x + blockIdx.x;   // [0,1024)
  int xcd = fid & 7, slot = fid >> 3;              // slot in [0,128)
  int bh = xcd * 8 + (slot >> 4);
  int qt = slot & 15;
  int b = bh >> 4, h = bh & 15;
  int tid = threadIdx.x, wave = tid >> 6, lane = tid & 63, l16 = lane & 15, quad = lane >> 4;
  int wq = wave * 64;

  const unsigned short* qh = wsc + QH_OFF + (size_t)bh * SEQ * DK;
  const unsigned short* kh = wsc + KH_OFF + (size_t)bh * SEQ * DK;
  const unsigned short* vt = wsc + VT_OFF + (size_t)bh * DK * SEQ;
  const unsigned short* pm = wsc + MSKF_OFF + (size_t)b * SEQ;

  // stage Q tile (128x64) into Ks region, read B-operand frags, then release
  #pragma unroll
  for (int kk = 0; kk < 2; ++kk)
    #pragma unroll
    for (int rnd = 0; rnd < 4; ++rnd) {
      int e = tid * 8 + rnd * 1024;
      int row = e >> 5, col = e & 31;
      gld_lds16(qh + (size_t)(qt * 128 + row) * DK + kk * 32 + col, Ks + kk * 4096 + e);
    }
  __syncthreads();
  bf16x8 qf[4][2];
  #pragma unroll
  for (int fq = 0; fq < 4; ++fq)
    #pragma unroll
    for (int kk = 0; kk < 2; ++kk)
      qf[fq][kk] = *(const bf16x8*)(Ks + kk * 4096 + (wq + fq * 16 + l16) * 32 + quad * 8);
  __syncthreads();   // all Q reads done before K(0) staging overwrites Ks

  // prologue: stage K(0) + mask(0) (only drain not covered by compute)
  #pragma unroll
  for (int kk = 0; kk < 2; ++kk)
    #pragma unroll
    for (int rnd = 0; rnd < 4; ++rnd) {
      int e = tid * 8 + rnd * 1024;
      int row = e >> 5, col = e & 31;
      gld_lds16(kh + (size_t)row * DK + kk * 32 + col, Ks + kk * 4096 + e);
    }
  if (tid < 16)
    gld_lds16(pm + tid * 8, MskB + tid * 8);
  __syncthreads();   // K(0)/mask(0) ready

  floatx4 o[4][4] = {};
  floatx4 osum[4] = {};          // denominator accumulators (mask-row MFMA)
  const floatx4 zero4 = {};

  union PU { unsigned int u[4][4]; bf16x8 v[4]; };   // [fq] x 4 dwords each

  #pragma unroll 1
  for (int jt = 0; jt < 16; ++jt) {
    // ---- Phase A: issue V(jt); QK^T + exp2 + pack + osum from Ks/MskB ----
    #pragma unroll
    for (int kk = 0; kk < 4; ++kk)
      #pragma unroll
      for (int rnd = 0; rnd < 2; ++rnd) {
        int e = tid * 8 + rnd * 1024;
        int row = e >> 5, col = e & 31;
        gld_lds16(vt + (size_t)row * SEQ + jt * 128 + kk * 32 + col, Vts + kk * 2048 + e);
      }

    PU pf[4];   // persists into Phase B
    #pragma unroll
    for (int w = 0; w < 4; ++w) {
      floatx4 s[2][4];
      #pragma unroll
      for (int f2 = 0; f2 < 2; ++f2) {
        int fk = 2 * w + f2;
        bf16x8 kf0 = *(const bf16x8*)(Ks +        (fk * 16 + l16) * 32 + quad * 8);
        bf16x8 kf1 = *(const bf16x8*)(Ks + 4096 + (fk * 16 + l16) * 32 + quad * 8);
        #pragma unroll
        for (int fq = 0; fq < 4; ++fq) {
          s[f2][fq] = __builtin_amdgcn_mfma_f32_16x16x32_bf16(kf0, qf[fq][0], zero4, 0, 0, 0);
          s[f2][fq] = __builtin_amdgcn_mfma_f32_16x16x32_bf16(kf1, qf[fq][1], s[f2][fq], 0, 0, 0);
        }
      }
      #pragma unroll
      for (int f2 = 0; f2 < 2; ++f2)
        #pragma unroll
        for (int fq = 0; fq < 4; ++fq)
          #pragma unroll
          for (int r = 0; r < 4; ++r)
            s[f2][fq][r] = __builtin_amdgcn_exp2f(s[f2][fq][r]);

      #pragma unroll
      for (int fq = 0; fq < 4; ++fq) {
        asm("v_cvt_pk_bf16_f32 %0, %1, %2" : "=v"(pf[w].u[fq][0]) : "v"(s[0][fq][0]), "v"(s[0][fq][1]));
        asm("v_cvt_pk_bf16_f32 %0, %1, %2" : "=v"(pf[w].u[fq][1]) : "v"(s[0][fq][2]), "v"(s[0][fq][3]));
        asm("v_cvt_pk_bf16_f32 %0, %1, %2" : "=v"(pf[w].u[fq][2]) : "v"(s[1][fq][0]), "v"(s[1][fq][1]));
        asm("v_cvt_pk_bf16_f32 %0, %1, %2" : "=v"(pf[w].u[fq][3]) : "v"(s[1][fq][2]), "v"(s[1][fq][3]));
      }

      // denominator: A = mask value in ALL 16 rows -> every C row holds
      // sum_k mask[k]*p[k][q]; broadcast LDS read (same addr for all l16)
      bf16x8 mvf = *(const bf16x8*)(MskB + w * 32 + quad * 8);
      #pragma unroll
      for (int fq = 0; fq < 4; ++fq)
        osum[fq] = __builtin_amdgcn_mfma_f32_16x16x32_bf16(mvf, pf[w].v[fq], osum[fq], 0, 0, 0);
    }

    __syncthreads();   // V(jt) landed (vmcnt, hidden under A); Ks/MskB reads done

    // ---- Phase B: issue K(jt+1)+mask; pure-PV MFMA cluster ----
    if (jt < 15) {
      const unsigned short* khn = kh + (size_t)(jt + 1) * 128 * DK;
      #pragma unroll
      for (int kk = 0; kk < 2; ++kk)
        #pragma unroll
        for (int rnd = 0; rnd < 4; ++rnd) {
          int e = tid * 8 + rnd * 1024;
          int row = e >> 5, col = e & 31;
          gld_lds16(khn + (size_t)row * DK + kk * 32 + col, Ks + kk * 4096 + e);
        }
      if (tid < 16)
        gld_lds16(pm + (jt + 1) * 128 + tid * 8, MskB + tid * 8);
    }

    __builtin_amdgcn_s_setprio(1);
    #pragma unroll
    for (int w = 0; w < 4; ++w)
      #pragma unroll
      for (int fd = 0; fd < 4; ++fd) {
        bf16x8 vf = *(const bf16x8*)(Vts + w * 2048 + (fd * 16 + l16) * 32 + quad * 8);
        #pragma unroll
        for (int fq = 0; fq < 4; ++fq)
          o[fd][fq] = __builtin_amdgcn_mfma_f32_16x16x32_bf16(vf, pf[w].v[fq], o[fd][fq], 0, 0, 0);
      }
    __builtin_amdgcn_s_setprio(0);

    __syncthreads();   // K(jt+1) landed (hidden under PV); Vts reads done
  }

  // every lane already holds its q's denominator (all osum rows identical)
  float inv[4];
  #pragma unroll
  for (int fq = 0; fq < 4; ++fq)
    inv[fq] = __builtin_amdgcn_rcpf(osum[fq][0]);

  unsigned short* Ot = smem;   // 128 q x 72 (64 d + 8 pad)
  #pragma unroll
  for (int fd = 0; fd < 4; ++fd)
    #pragma unroll
    for (int fq = 0; fq < 4; ++fq)
      #pragma unroll
      for (int r = 0; r < 4; ++r) {
        int q = wq + fq * 16 + l16;
        int d = fd * 16 + quad * 4 + r;
        Ot[q * 72 + d] = f2bf(o[fd][fq][r] * inv[fq]);
      }
  __syncthreads();
  unsigned short* oc = ws + OC_OFF;
  #pragma unroll
  for (int rr = 0; rr < 8; ++rr) {
    int e = rr * 1024 + tid * 8;
    int q = e >> 6, off = e & 63;
    uint4 val = *(const uint4*)(Ot + q * 72 + off);
    *(uint4*)(oc + ((size_t)(b * SEQ + qt * 128 + q)) * DMODEL + h * DK + off) = val;
  }
}

// ---------------------------------------------------------------------------
// Output projection: out = Ocomb Wo^T + bo  (fp32 out)
// R9: same XCD-locality remap as proj_gemm z<2. R11: dbuf K-loop (32 KB LDS).
// ---------------------------------------------------------------------------
__global__ __launch_bounds__(256) void out_gemm(
    const unsigned short* __restrict__ wsc, const float* __restrict__ bo,
    float* __restrict__ out)
{
  __shared__ unsigned short smem[16384];
  int flat = blockIdx.y * 8 + blockIdx.x;   // [0,512), hw xcd = flat & 7
  int xcd = flat & 7, slot = flat >> 3;
  int m_t = xcd * 8 + (slot >> 3);
  int n_t = slot & 7;
  int m0 = m_t * 128, n0 = n_t * 128;
  floatx4 acc[4][4] = {};
  gemm_core_128(wsc + OC_OFF, wsc + WO_OFF, m0, n0, smem, acc);

  int tid = threadIdx.x, lane = tid & 63, l16 = lane & 15, quad = lane >> 4;
  int wave = tid >> 6, wm = wave >> 1, wn = wave & 1;
  #pragma unroll
  for (int fn = 0; fn < 4; ++fn) {
    int n = n0 + wn * 64 + fn * 16 + l16;
    float bvv = bo[n];
    #pragma unroll
    for (int fm = 0; fm < 4; ++fm)
      #pragma unroll
      for (int r = 0; r < 4; ++r) {
        int m = m0 + wm * 64 + fm * 16 + quad * 4 + r;
        out[(size_t)m * DMODEL + n] = acc[fm][fn][r] + bvv;
      }
  }
}

// ---------------------------------------------------------------------------
extern "C" void kernel_launch(void* const* d_in, const int* in_sizes, int n_in,
                              void* d_out, int out_size, void* d_ws, size_t ws_size,
                              hipStream_t stream) {
  const float* Q    = (const float*)d_in[0];
  const float* K    = (const float*)d_in[1];
  const float* V    = (const float*)d_in[2];
  const float* bq   = (const float*)d_in[5];
  const float* bk   = (const float*)d_in[7];
  const float* bv   = (const float*)d_in[9];
  const float* bo   = (const float*)d_in[11];
  unsigned short* ws = (unsigned short*)d_ws;
  float* out = (float*)d_out;

  CastArgs ca;
  ca.src[0] = Q;  ca.src[1] = K;  ca.src[2] = V;
  ca.src[3] = (const float*)d_in[4]; ca.src[4] = (const float*)d_in[6];
  ca.src[5] = (const float*)d_in[8]; ca.src[6] = (const float*)d_in[10];
  ca.src[7] = (const float*)d_in[3];   // mask ints
  ca.off[0] = QB_OFF; ca.off[1] = KB_OFF; ca.off[2] = VB_OFF;
  ca.off[3] = WQ_OFF; ca.off[4] = WK_OFF; ca.off[5] = WV_OFF; ca.off[6] = WO_OFF;
  ca.off[7] = MSKF_OFF;
  ca.n[0] = ca.n[1] = ca.n[2] = 8388608u;
  ca.n[3] = ca.n[4] = ca.n[5] = ca.n[6] = 1048576u;
  ca.n[7] = 8192u;

  hipLaunchKernelGGL(cast_bf16, dim3(2048, 8), dim3(256), 0, stream, ca, ws);
  hipLaunchKernelGGL(proj_gemm, dim3(8, 64, 3), dim3(256), 0, stream, ws, ws, bq, bk, bv);
  hipLaunchKernelGGL(attn_fused, dim3(16, 64), dim3(128), 0, stream, ws, ws);
  hipLaunchKernelGGL(out_gemm, dim3(8, 64), dim3(256), 0, stream, ws, bo, out);
}